// Round 11
// baseline (198.679 us; speedup 1.0000x reference)
//
#include <hip/hip_runtime.h>

typedef _Float16 f16;
typedef _Float16 f16x4 __attribute__((ext_vector_type(4)));
typedef _Float16 f16x8 __attribute__((ext_vector_type(8)));
typedef float    f32x4 __attribute__((ext_vector_type(4)));
typedef float    f32x16 __attribute__((ext_vector_type(16)));
typedef unsigned int u32x4 __attribute__((ext_vector_type(4)));

#define QK_SCALE 11.5416528f  // 8 * log2(e): scores pre-scaled into exp2 domain

__device__ __forceinline__ void g2l16(const void* g, void* l) {
  __builtin_amdgcn_global_load_lds(
      (__attribute__((address_space(1))) const unsigned int*)g,
      (__attribute__((address_space(3))) unsigned int*)l, 16, 0, 0);
}

__device__ __forceinline__ f32x4 mfma16(f16x8 a, f16x8 b, f32x4 c) {
  return __builtin_amdgcn_mfma_f32_16x16x32_f16(a, b, c, 0, 0, 0);
}
__device__ __forceinline__ f32x16 mfma32(f16x8 a, f16x8 b, f32x16 c) {
  return __builtin_amdgcn_mfma_f32_32x32x16_f16(a, b, c, 0, 0, 0);
}
__device__ __forceinline__ unsigned pkrtz(float a, float b) {
  auto t = __builtin_amdgcn_cvt_pkrtz(a, b);  // __fp16 ext_vector_type(2)
  return *(unsigned*)&t;
}
// v_permlane32_swap_b32: a.upper32lanes <-> b.lower32lanes (modifies both)
__device__ __forceinline__ void swap32(unsigned& a, unsigned& b) {
  asm volatile("v_permlane32_swap_b32 %0, %1" : "+v"(a), "+v"(b));
}

#define WAIT_BARRIER(N)                                        \
  do {                                                         \
    asm volatile("s_waitcnt vmcnt(" #N ")" ::: "memory");      \
    __builtin_amdgcn_sched_barrier(0);                         \
    __builtin_amdgcn_s_barrier();                              \
    __builtin_amdgcn_sched_barrier(0);                         \
  } while (0)

// XOR-swizzled LDS offsets (f16 units). Rows of 64 f16 (8x16B chunks) / 32 f16 (4x16B chunks).
__device__ __forceinline__ int swz64(int row, int c) { return row * 64 + ((c ^ (row & 7)) << 3); }
__device__ __forceinline__ int swz32(int row, int c) { return row * 32 + ((c ^ ((row >> 1) & 3)) << 3); }

// ---------------- fp32 -> fp16 hi/lo split (vectorized) ----------------
__global__ __launch_bounds__(256) void k_split(const float* __restrict__ in,
                                               f16* __restrict__ hi, f16* __restrict__ lo, int n4) {
  int i = blockIdx.x * 256 + threadIdx.x;
  if (i >= n4) return;
  f32x4 v = ((const f32x4*)in)[i];
  f16x4 h, l;
#pragma unroll
  for (int j = 0; j < 4; ++j) {
    f16 hv = (f16)v[j];
    h[j] = hv;
    l[j] = (f16)(v[j] - (float)hv);
  }
  ((f16x4*)hi)[i] = h;
  ((f16x4*)lo)[i] = l;
}

// ---------------- transpose fp32 [K][N] -> fp16 [N][K] (hi, optional lo) ----------------
template <bool WLO>
__global__ __launch_bounds__(256) void k_transpose_split(const float* __restrict__ in, int K, int N,
                                                         f16* __restrict__ oh, f16* __restrict__ ol) {
  __shared__ float t[32][33];
  const int tx = threadIdx.x, ty = threadIdx.y;
  const int n0 = blockIdx.x * 32, k0 = blockIdx.y * 32;
#pragma unroll
  for (int j = 0; j < 4; ++j)
    t[ty + j * 8][tx] = in[(size_t)(k0 + ty + j * 8) * N + n0 + tx];
  __syncthreads();
#pragma unroll
  for (int j = 0; j < 4; ++j) {
    float v = t[tx][ty + j * 8];
    f16 hv = (f16)v;
    size_t o = (size_t)(n0 + ty + j * 8) * K + k0 + tx;
    oh[o] = hv;
    if (WLO) ol[o] = (f16)(v - (float)hv);
  }
}

// ---------------- GEMM: C[M,N] = A[M,K+] * B[K+,N], B given transposed [N][K+] -----------
// ks = row stride of A and B-T (allows split-K subviews).
// Pipeline: non-split = 3-buffer LDS, stage dist 2, counted vmcnt(4) (4 loads/thread/stage);
//           split     = 2-buffer, stage-under-compute, vmcnt(0).
// EPI 0: qkv scatter; Q tiles (bn<4) 3-term split; K,V tiles 1-term
// EPI 1: relu -> fp16 out
// EPI 3: split-K pair: bn>>2 = K-half; fp16 partials to outH (half0, +bias) / outH2 (half1)
template <int EPI, bool SPLIT>
__global__ __launch_bounds__(256, SPLIT ? 2 : 3) void k_gemm(
    const f16* __restrict__ Ah, const f16* __restrict__ Al,
    const f16* __restrict__ Bh, const f16* __restrict__ Bl,
    const float* __restrict__ bias,
    f16* __restrict__ outH, f16* __restrict__ outH2,
    f16* __restrict__ oqh, f16* __restrict__ oql,
    f16* __restrict__ okh, f16* __restrict__ ovT,
    int M, int N, int K, int ks) {
  constexpr int NBUF = SPLIT ? 2 : 3;
  constexpr int NB = SPLIT ? 2 : 1;
  __shared__ f16 As[NBUF][NB][128 * 32];
  __shared__ f16 Bs[NBUF][NB][128 * 32];

  const int tid = threadIdx.x;
  const int bm = blockIdx.x, bn = blockIdx.y;
  const int bnc = (EPI == 3) ? (bn & 3) : bn;
  const int half = (EPI == 3) ? (bn >> 2) : 0;
  const int hoff = half * 1024;
  const int w = tid >> 6, lane = tid & 63;
  const int wr = w >> 1, wc = w & 1;
  const int lrow = lane & 15, lgrp = lane >> 4;

  // only Q-output tiles need the hi/lo emulated-fp32 path
  const bool useLo = SPLIT && !(EPI == 0 && bn >= 4);

  f32x4 acc[4][4] = {};

  auto stg = [&](int bf, int kt) {
    const int kk = kt << 5;
#pragma unroll
    for (int c = 0; c < 2; ++c) {
      const int i = tid + (c << 8);
      const int row = i >> 2;
      const int gch = ((i & 3) ^ ((i >> 3) & 3)) << 3;  // swizzled source chunk
      const size_t aoff = (size_t)(bm * 128 + row) * ks + hoff + kk + gch;
      const size_t boff = (size_t)(bnc * 128 + row) * ks + hoff + kk + gch;
      g2l16(Ah + aoff, &As[bf][0][i * 8]);
      g2l16(Bh + boff, &Bs[bf][0][i * 8]);
      if (SPLIT)
        if (useLo) {
          g2l16(Al + aoff, &As[bf][1][i * 8]);
          g2l16(Bl + boff, &Bs[bf][1][i * 8]);
        }
    }
  };

  auto compute = [&](int bf) {
    f16x8 a0[4], a1[4], b0[4], b1[4];
#pragma unroll
    for (int mf = 0; mf < 4; ++mf) {
      const int off = swz32(wr * 64 + mf * 16 + lrow, lgrp);
      a0[mf] = *(const f16x8*)&As[bf][0][off];
      if (SPLIT)
        if (useLo) a1[mf] = *(const f16x8*)&As[bf][SPLIT ? 1 : 0][off];
    }
#pragma unroll
    for (int nf = 0; nf < 4; ++nf) {
      const int off = swz32(wc * 64 + nf * 16 + lrow, lgrp);
      b0[nf] = *(const f16x8*)&Bs[bf][0][off];
      if (SPLIT)
        if (useLo) b1[nf] = *(const f16x8*)&Bs[bf][SPLIT ? 1 : 0][off];
    }
#pragma unroll
    for (int mf = 0; mf < 4; ++mf)
#pragma unroll
      for (int nf = 0; nf < 4; ++nf) {
        acc[mf][nf] = mfma16(a0[mf], b0[nf], acc[mf][nf]);
        if (SPLIT)
          if (useLo) {
            acc[mf][nf] = mfma16(a0[mf], b1[nf], acc[mf][nf]);
            acc[mf][nf] = mfma16(a1[mf], b0[nf], acc[mf][nf]);
          }
      }
  };

  const int nkt = K >> 5;
  if constexpr (!SPLIT) {
    stg(0, 0);
    stg(1, 1);
    WAIT_BARRIER(4);  // 8 outstanding -> 4: stage(0) landed (all waves), barrier publishes
    for (int kt = 0; kt < nkt; ++kt) {
      const int cur = kt % 3;
      const bool more2 = (kt + 2 < nkt);
      if (more2) stg((kt + 2) % 3, kt + 2);
      compute(cur);
      if (kt + 1 < nkt) {
        if (more2) WAIT_BARRIER(4);  // stage(kt+1) confirmed; stage(kt+2) stays in flight
        else       WAIT_BARRIER(0);
      }
    }
  } else {
    stg(0, 0);
    WAIT_BARRIER(0);
    for (int kt = 0; kt < nkt; ++kt) {
      const int cur = kt & 1;
      if (kt + 1 < nkt) stg(cur ^ 1, kt + 1);
      compute(cur);
      if (kt + 1 < nkt) WAIT_BARRIER(0);  // stage landed under compute
    }
  }

  const int rowbase = bm * 128 + wr * 64 + lgrp * 4;
  const int colbase = bnc * 128 + wc * 64 + lrow;
#pragma unroll
  for (int mf = 0; mf < 4; ++mf) {
#pragma unroll
    for (int nf = 0; nf < 4; ++nf) {
      const int gc = colbase + nf * 16;
      const float bv = (EPI == 3 && half) ? 0.f : bias[gc];
#pragma unroll
      for (int r = 0; r < 4; ++r) {
        const int gr = rowbase + mf * 16 + r;
        const float val = acc[mf][nf][r] + bv;
        if (EPI == 0) {
          const int bb = gr >> 11, tok = gr & 2047;
          const int kind = gc >> 9, hh = (gc >> 6) & 7, dd = gc & 63;
          const size_t bhp = (size_t)((bb << 3) + hh);
          const size_t qidx = (bhp * 2048 + tok) * 64 + dd;
          if (kind == 0) {
            const float sv = val * QK_SCALE;  // fold score scale + log2e into q
            const f16 hv = (f16)sv;
            oqh[qidx] = hv; oql[qidx] = (f16)(sv - (float)hv);
          } else if (kind == 1) {
            okh[qidx] = (f16)val;
          } else {
            ovT[(bhp * 64 + dd) * 2048 + tok] = (f16)val;
          }
        } else if (EPI == 1) {
          outH[(size_t)gr * N + gc] = (f16)fmaxf(val, 0.f);
        } else {
          f16* o = half ? outH2 : outH;
          o[(size_t)gr * N + gc] = (f16)val;
        }
      }
    }
  }
}

// ---------------- fused flash attention: 32x32 MFMA, in-reg softmax, T15 + pair-barriers --
// 1D grid 512, XCD-aware bh-major swizzle. Block 256 = 4 waves; wave owns 32 q-rows.
// Pair scheme: stage tiles t+2,t+3 at pair start; ONE vmcnt(0)+s_barrier per 2 tiles
// (stages land under ~2 iters of compute). T15: qk(t+1) issues under sm_pv(t);
// qk(t+2) right after the barrier. K/V 4-buffer LDS (64 KB). fp16 output.
__global__ __launch_bounds__(256, 2) void k_attn(
    const f16* __restrict__ Qh, const f16* __restrict__ Ql,
    const f16* __restrict__ Kh, const f16* __restrict__ Vt,
    f16* __restrict__ out) {
  __shared__ f16 sK[4][64 * 64], sV[4][64 * 64];

  const int tid = threadIdx.x;
  const int wg = (blockIdx.x & 7) * 64 + (blockIdx.x >> 3);
  const int bh = wg >> 4, qt = wg & 15;
  const int w = tid >> 6, lane = tid & 63;
  const int lh = lane & 31, hh = lane >> 5;

  // Q fragments (issued before stages so the prologue drain covers them too)
  const int qrow = qt * 128 + w * 32 + lh;
  const size_t qoff = ((size_t)bh * 2048 + qrow) * 64;
  f16x8 qh8[4], ql8[4];
#pragma unroll
  for (int d = 0; d < 4; ++d) {
    const size_t o = qoff + d * 16 + hh * 8;
    qh8[d] = *(const f16x8*)(Qh + o);
    ql8[d] = *(const f16x8*)(Ql + o);
  }

  auto stage = [&](int b, int kt) {
    const size_t koff = ((size_t)bh * 2048 + (size_t)kt * 64) * 64;
    const size_t voff = (size_t)bh * 64 * 2048 + (size_t)kt * 64;
#pragma unroll
    for (int c = 0; c < 2; ++c) {
      const int i = tid + (c << 8);
      const int row = i >> 3;
      const int gch = ((i & 7) ^ (row & 7)) << 3;
      g2l16(Kh + koff + (size_t)row * 64 + gch, &sK[b][i * 8]);
      g2l16(Vt + voff + (size_t)row * 2048 + gch, &sV[b][i * 8]);
    }
  };

  stage(0, 0);
  stage(1, 1);

  float m_run = -3e38f;
  float l_run = 0.f;
  f32x16 oacc[2] = {};
  const f32x16 kZero = {};
  f32x16 sA[2] = {}, sB[2] = {};

  // QK MFMA issue for one tile (buffer bi) into s[2]; first MFMA uses zero-C (no resets)
  auto qk = [&](f32x16 (&s)[2], int bi) {
    __builtin_amdgcn_s_setprio(1);
    {
      const f16x8 k0 = *(const f16x8*)&sK[bi][swz64(lh, hh)];
      const f16x8 k1 = *(const f16x8*)&sK[bi][swz64(32 + lh, hh)];
      s[0] = mfma32(k0, qh8[0], kZero);
      s[0] = mfma32(k0, ql8[0], s[0]);
      s[1] = mfma32(k1, qh8[0], kZero);
      s[1] = mfma32(k1, ql8[0], s[1]);
    }
#pragma unroll
    for (int d = 1; d < 4; ++d) {
      const f16x8 k0 = *(const f16x8*)&sK[bi][swz64(lh, d * 2 + hh)];
      const f16x8 k1 = *(const f16x8*)&sK[bi][swz64(32 + lh, d * 2 + hh)];
      s[0] = mfma32(k0, qh8[d], s[0]);
      s[0] = mfma32(k0, ql8[d], s[0]);
      s[1] = mfma32(k1, qh8[d], s[1]);
      s[1] = mfma32(k1, ql8[d], s[1]);
    }
    __builtin_amdgcn_s_setprio(0);
  };

  // softmax + PV for current tile (registers s, buffer bi)
  auto sm_pv = [&](f32x16 (&s)[2], int bi) {
    float mt = s[0][0];
#pragma unroll
    for (int r = 0; r < 16; ++r) { mt = fmaxf(mt, s[0][r]); mt = fmaxf(mt, s[1][r]); }
    mt = fmaxf(mt, __shfl_xor(mt, 32, 64));
    float mcur = m_run;
    if (!__all(mt <= mcur + 8.0f)) {  // defer-max
      const float mnew = fmaxf(mcur, mt);
      const float corr = __builtin_amdgcn_exp2f(mcur - mnew);
      m_run = mnew;
      l_run *= corr;
      oacc[0] = oacc[0] * corr;
      oacc[1] = oacc[1] * corr;
      mcur = mnew;
    }
    float ps = 0.f;
    unsigned pk0[8], pk1[8];
#pragma unroll
    for (int i = 0; i < 8; ++i) {
      const float a0 = __builtin_amdgcn_exp2f(s[0][2 * i] - mcur);
      const float a1 = __builtin_amdgcn_exp2f(s[0][2 * i + 1] - mcur);
      const float b0 = __builtin_amdgcn_exp2f(s[1][2 * i] - mcur);
      const float b1 = __builtin_amdgcn_exp2f(s[1][2 * i + 1] - mcur);
      ps += (a0 + a1) + (b0 + b1);
      pk0[i] = pkrtz(a0, a1);
      pk1[i] = pkrtz(b0, b1);
    }
    ps += __shfl_xor(ps, 32, 64);
    l_run += ps;

    swap32(pk0[0], pk0[2]); swap32(pk0[1], pk0[3]);
    swap32(pk0[4], pk0[6]); swap32(pk0[5], pk0[7]);
    swap32(pk1[0], pk1[2]); swap32(pk1[1], pk1[3]);
    swap32(pk1[4], pk1[6]); swap32(pk1[5], pk1[7]);

    u32x4 pbu[4];
    pbu[0] = (u32x4){pk0[0], pk0[1], pk0[2], pk0[3]};
    pbu[1] = (u32x4){pk0[4], pk0[5], pk0[6], pk0[7]};
    pbu[2] = (u32x4){pk1[0], pk1[1], pk1[2], pk1[3]};
    pbu[3] = (u32x4){pk1[4], pk1[5], pk1[6], pk1[7]};

    __builtin_amdgcn_s_setprio(1);
#pragma unroll
    for (int s2 = 0; s2 < 4; ++s2) {
      const f16x8 pb = *(const f16x8*)&pbu[s2];
#pragma unroll
      for (int db = 0; db < 2; ++db) {
        const f16x8 v = *(const f16x8*)&sV[bi][swz64(db * 32 + lh, s2 * 2 + hh)];
        oacc[db] = mfma32(v, pb, oacc[db]);
      }
    }
    __builtin_amdgcn_s_setprio(0);
  };

  // prologue: everything (Q + tiles 0,1) drained, published by barrier
  WAIT_BARRIER(0);
  qk(sA, 0);

  for (int t = 0; t < 32; t += 2) {
    if (t + 2 < 32) {
      stage((t + 2) & 3, t + 2);
      stage((t + 3) & 3, t + 3);
    }
    qk(sB, (t + 1) & 3);   // issues under sm_pv(sA) below (T15)
    sm_pv(sA, t & 3);
    sm_pv(sB, (t + 1) & 3);
    if (t + 2 < 32) {
      WAIT_BARRIER(0);     // stages issued at pair start: landed under ~2 tiles of compute
      qk(sA, (t + 2) & 3);
    }
  }

  const int b = bh >> 3, hd = bh & 7;
  const float inv = 1.0f / l_run;
  const int trow = b * 2048 + qt * 128 + w * 32 + lh;
  f16* po = out + (size_t)trow * 512 + hd * 64;
#pragma unroll
  for (int db = 0; db < 2; ++db)
#pragma unroll
    for (int rq = 0; rq < 4; ++rq) {
      f16x4 o;
#pragma unroll
      for (int j = 0; j < 4; ++j) o[j] = (f16)(oacc[db][rq * 4 + j] * inv);
      *(f16x4*)(po + db * 32 + rq * 8 + hh * 4) = o;
    }
}

// ---------------- LN1: y = LN(x + attn) -> fp16 only (4 rows/block, wave per row) ---------
__global__ __launch_bounds__(256) void k_ln1(const float* __restrict__ X, const f16* __restrict__ R,
                                             const float* __restrict__ g, const float* __restrict__ be,
                                             f16* __restrict__ outH) {
  const int row = blockIdx.x * 4 + (threadIdx.x >> 6);
  const int t = threadIdx.x & 63;
  const size_t base = (size_t)row * 512 + t * 8;
  f32x4 x0 = *(const f32x4*)(X + base);
  f32x4 x1 = *(const f32x4*)(X + base + 4);
  const f16x8 r = *(const f16x8*)(R + base);
#pragma unroll
  for (int j = 0; j < 4; ++j) { x0[j] += (float)r[j]; x1[j] += (float)r[j + 4]; }
  float s = 0.f, ss = 0.f;
#pragma unroll
  for (int j = 0; j < 4; ++j) { s += x0[j] + x1[j]; ss += x0[j] * x0[j] + x1[j] * x1[j]; }
#pragma unroll
  for (int o = 32; o; o >>= 1) {
    s += __shfl_xor(s, o, 64);
    ss += __shfl_xor(ss, o, 64);
  }
  const float mean = s * (1.f / 512.f);
  const float var = ss * (1.f / 512.f) - mean * mean;
  const float rs = rsqrtf(var + 1e-5f);
  f32x4 g0 = *(const f32x4*)(g + t * 8);
  f32x4 g1v = *(const f32x4*)(g + t * 8 + 4);
  f32x4 b0 = *(const f32x4*)(be + t * 8);
  f32x4 b1 = *(const f32x4*)(be + t * 8 + 4);
  f16x8 hx;
#pragma unroll
  for (int j = 0; j < 4; ++j) {
    hx[j] = (f16)((x0[j] - mean) * rs * g0[j] + b0[j]);
    hx[j + 4] = (f16)((x1[j] - mean) * rs * g1v[j] + b1[j]);
  }
  *(f16x8*)(outH + base) = hx;
}

// ---------------- LN2: y = LN(x1 + ff0 + ff1) -> fp32 out (ff partials fp16) --------------
__global__ __launch_bounds__(256) void k_ln2(const f16* __restrict__ Xh,
                                             const f16* __restrict__ R0, const f16* __restrict__ R1,
                                             const float* __restrict__ g, const float* __restrict__ be,
                                             float* __restrict__ out) {
  const int row = blockIdx.x * 4 + (threadIdx.x >> 6);
  const int t = threadIdx.x & 63;
  const size_t base = (size_t)row * 512 + t * 8;
  const f16x8 xv = *(const f16x8*)(Xh + base);
  const f16x8 r0 = *(const f16x8*)(R0 + base);
  const f16x8 r1 = *(const f16x8*)(R1 + base);
  f32x4 x0, x1;
#pragma unroll
  for (int j = 0; j < 4; ++j) {
    x0[j] = (float)xv[j] + (float)r0[j] + (float)r1[j];
    x1[j] = (float)xv[j + 4] + (float)r0[j + 4] + (float)r1[j + 4];
  }
  float s = 0.f, ss = 0.f;
#pragma unroll
  for (int j = 0; j < 4; ++j) { s += x0[j] + x1[j]; ss += x0[j] * x0[j] + x1[j] * x1[j]; }
#pragma unroll
  for (int o = 32; o; o >>= 1) {
    s += __shfl_xor(s, o, 64);
    ss += __shfl_xor(ss, o, 64);
  }
  const float mean = s * (1.f / 512.f);
  const float var = ss * (1.f / 512.f) - mean * mean;
  const float rs = rsqrtf(var + 1e-5f);
  f32x4 g0 = *(const f32x4*)(g + t * 8);
  f32x4 g1v = *(const f32x4*)(g + t * 8 + 4);
  f32x4 b0 = *(const f32x4*)(be + t * 8);
  f32x4 b1 = *(const f32x4*)(be + t * 8 + 4);
  f32x4 y0 = (x0 - mean) * rs * g0 + b0;
  f32x4 y1 = (x1 - mean) * rs * g1v + b1;
  *(f32x4*)(out + base) = y0;
  *(f32x4*)(out + base + 4) = y1;
}

extern "C" void kernel_launch(void* const* d_in, const int* in_sizes, int n_in,
                              void* d_out, int out_size, void* d_ws, size_t ws_size,
                              hipStream_t stream) {
  (void)in_sizes; (void)n_in; (void)out_size;
  const float* x = (const float*)d_in[0];
  const float* w_qkv = (const float*)d_in[1];
  const float* b_qkv = (const float*)d_in[2];
  const float* w1 = (const float*)d_in[3];
  const float* b1 = (const float*)d_in[4];
  const float* w2 = (const float*)d_in[5];
  const float* b2 = (const float*)d_in[6];
  const float* g1 = (const float*)d_in[7];
  const float* be1 = (const float*)d_in[8];
  const float* g2 = (const float*)d_in[9];
  const float* be2 = (const float*)d_in[10];
  float* out = (float*)d_out;

  char* p = (char*)d_ws;
  auto take = [&](size_t bytes) {
    char* r = p;
    p += (bytes + 255) & ~(size_t)255;
    return r;
  };
  f16* xh = (f16*)take(8192ull * 512 * 2);
  f16* xl = (f16*)take(8192ull * 512 * 2);
  f16* wqkvTh = (f16*)take(1536ull * 512 * 2);
  f16* wqkvTl = (f16*)take(1536ull * 512 * 2);
  f16* w1T = (f16*)take(2048ull * 512 * 2);
  f16* w2T = (f16*)take(512ull * 2048 * 2);
  f16* qh = (f16*)take(32ull * 2048 * 64 * 2);
  f16* ql = (f16*)take(32ull * 2048 * 64 * 2);
  f16* kh = (f16*)take(32ull * 2048 * 64 * 2);
  f16* vT = (f16*)take(32ull * 64 * 2048 * 2);
  f16* attnH = (f16*)take(8192ull * 512 * 2);
  f16* x1h = (f16*)take(8192ull * 512 * 2);
  f16* ffb0 = (f16*)take(8192ull * 512 * 2);
  f16* ffb1 = (f16*)take(8192ull * 512 * 2);
  // reuse: hbuf [8192][2048]f16 = 33.6MB spans qh,ql,kh,vT (all dead after attn)
  f16* hbuf = qh;

  if ((size_t)(p - (char*)d_ws) > ws_size) return;  // insufficient workspace -> loud validation fail

  dim3 tb(32, 8);
  k_split<<<4096, 256, 0, stream>>>(x, xh, xl, 8192 * 512 / 4);
  k_transpose_split<true><<<dim3(1536 / 32, 512 / 32), tb, 0, stream>>>(w_qkv, 512, 1536, wqkvTh, wqkvTl);
  k_transpose_split<false><<<dim3(2048 / 32, 512 / 32), tb, 0, stream>>>(w1, 512, 2048, w1T, nullptr);
  k_transpose_split<false><<<dim3(512 / 32, 2048 / 32), tb, 0, stream>>>(w2, 2048, 512, w2T, nullptr);

  k_gemm<0, true><<<dim3(64, 12), 256, 0, stream>>>(xh, xl, wqkvTh, wqkvTl, b_qkv,
                                                    nullptr, nullptr, qh, ql, kh, vT,
                                                    8192, 1536, 512, 512);
  k_attn<<<512, 256, 0, stream>>>(qh, ql, kh, vT, attnH);
  k_ln1<<<2048, 256, 0, stream>>>(x, attnH, g1, be1, x1h);
  k_gemm<1, false><<<dim3(64, 16), 256, 0, stream>>>(x1h, nullptr, w1T, nullptr, b1,
                                                     hbuf, nullptr, nullptr, nullptr, nullptr, nullptr,
                                                     8192, 2048, 512, 512);
  k_gemm<3, false><<<dim3(64, 8), 256, 0, stream>>>(hbuf, nullptr, w2T, nullptr, b2,
                                                    ffb0, ffb1, nullptr, nullptr, nullptr, nullptr,
                                                    8192, 512, 1024, 2048);
  k_ln2<<<2048, 256, 0, stream>>>(x1h, ffb0, ffb1, g2, be2, out);
}

// Round 12
// 190.357 us; speedup vs baseline: 1.0437x; 1.0437x over previous
//
#include <hip/hip_runtime.h>

typedef _Float16 f16;
typedef _Float16 f16x4 __attribute__((ext_vector_type(4)));
typedef _Float16 f16x8 __attribute__((ext_vector_type(8)));
typedef float    f32x4 __attribute__((ext_vector_type(4)));
typedef float    f32x16 __attribute__((ext_vector_type(16)));
typedef unsigned int u32x4 __attribute__((ext_vector_type(4)));

#define QK_SCALE 11.5416528f  // 8 * log2(e): scores pre-scaled into exp2 domain

__device__ __forceinline__ void g2l16(const void* g, void* l) {
  __builtin_amdgcn_global_load_lds(
      (__attribute__((address_space(1))) const unsigned int*)g,
      (__attribute__((address_space(3))) unsigned int*)l, 16, 0, 0);
}

__device__ __forceinline__ f32x4 mfma16(f16x8 a, f16x8 b, f32x4 c) {
  return __builtin_amdgcn_mfma_f32_16x16x32_f16(a, b, c, 0, 0, 0);
}
__device__ __forceinline__ f32x16 mfma32(f16x8 a, f16x8 b, f32x16 c) {
  return __builtin_amdgcn_mfma_f32_32x32x16_f16(a, b, c, 0, 0, 0);
}
__device__ __forceinline__ unsigned pkrtz(float a, float b) {
  auto t = __builtin_amdgcn_cvt_pkrtz(a, b);  // __fp16 ext_vector_type(2)
  return *(unsigned*)&t;
}
// v_permlane32_swap_b32: a.upper32lanes <-> b.lower32lanes (modifies both)
__device__ __forceinline__ void swap32(unsigned& a, unsigned& b) {
  asm volatile("v_permlane32_swap_b32 %0, %1" : "+v"(a), "+v"(b));
}

// Used ONLY in attn (few barriers, VALU-heavy phases). In GEMM loops the
// sched_barrier(0) pinning is the m141 regression -- plain __syncthreads there.
#define WAIT_BARRIER(N)                                        \
  do {                                                         \
    asm volatile("s_waitcnt vmcnt(" #N ")" ::: "memory");      \
    __builtin_amdgcn_sched_barrier(0);                         \
    __builtin_amdgcn_s_barrier();                              \
    __builtin_amdgcn_sched_barrier(0);                         \
  } while (0)

// XOR-swizzled LDS offsets (f16 units). Rows of 64 f16 (8x16B chunks) / 32 f16 (4x16B chunks).
__device__ __forceinline__ int swz64(int row, int c) { return row * 64 + ((c ^ (row & 7)) << 3); }
__device__ __forceinline__ int swz32(int row, int c) { return row * 32 + ((c ^ ((row >> 1) & 3)) << 3); }

// ---------------- fp32 -> fp16 hi/lo split (vectorized) ----------------
__global__ __launch_bounds__(256) void k_split(const float* __restrict__ in,
                                               f16* __restrict__ hi, f16* __restrict__ lo, int n4) {
  int i = blockIdx.x * 256 + threadIdx.x;
  if (i >= n4) return;
  f32x4 v = ((const f32x4*)in)[i];
  f16x4 h, l;
#pragma unroll
  for (int j = 0; j < 4; ++j) {
    f16 hv = (f16)v[j];
    h[j] = hv;
    l[j] = (f16)(v[j] - (float)hv);
  }
  ((f16x4*)hi)[i] = h;
  ((f16x4*)lo)[i] = l;
}

// ---------------- transpose fp32 [K][N] -> fp16 [N][K] (hi, optional lo) ----------------
template <bool WLO>
__global__ __launch_bounds__(256) void k_transpose_split(const float* __restrict__ in, int K, int N,
                                                         f16* __restrict__ oh, f16* __restrict__ ol) {
  __shared__ float t[32][33];
  const int tx = threadIdx.x, ty = threadIdx.y;
  const int n0 = blockIdx.x * 32, k0 = blockIdx.y * 32;
#pragma unroll
  for (int j = 0; j < 4; ++j)
    t[ty + j * 8][tx] = in[(size_t)(k0 + ty + j * 8) * N + n0 + tx];
  __syncthreads();
#pragma unroll
  for (int j = 0; j < 4; ++j) {
    float v = t[tx][ty + j * 8];
    f16 hv = (f16)v;
    size_t o = (size_t)(n0 + ty + j * 8) * K + k0 + tx;
    oh[o] = hv;
    if (WLO) ol[o] = (f16)(v - (float)hv);
  }
}

// ---------------- GEMM: C[M,N] = A[M,K+] * B[K+,N], B given transposed [N][K+] -----------
// ks = row stride of A and B-T (allows split-K subviews).
// 2-buffer LDS double-buffering: stage(kt+1) issues, compute(kt) overlaps it, ONE
// __syncthreads per iter (its implicit vmcnt(0) drain is covered by compute).
// EPI 0: qkv scatter; Q tiles (bn<4) 3-term split; K,V tiles 1-term
// EPI 1: relu -> fp16 out
// EPI 3: split-K pair: bn>>2 = K-half; fp16 partials to outH (half0, +bias) / outH2 (half1)
template <int EPI, bool SPLIT>
__global__ __launch_bounds__(256, SPLIT ? 2 : 3) void k_gemm(
    const f16* __restrict__ Ah, const f16* __restrict__ Al,
    const f16* __restrict__ Bh, const f16* __restrict__ Bl,
    const float* __restrict__ bias,
    f16* __restrict__ outH, f16* __restrict__ outH2,
    f16* __restrict__ oqh, f16* __restrict__ oql,
    f16* __restrict__ okh, f16* __restrict__ ovT,
    int M, int N, int K, int ks) {
  constexpr int NB = SPLIT ? 2 : 1;
  __shared__ f16 As[2][NB][128 * 32];
  __shared__ f16 Bs[2][NB][128 * 32];

  const int tid = threadIdx.x;
  const int bm = blockIdx.x, bn = blockIdx.y;
  const int bnc = (EPI == 3) ? (bn & 3) : bn;
  const int half = (EPI == 3) ? (bn >> 2) : 0;
  const int hoff = half * 1024;
  const int w = tid >> 6, lane = tid & 63;
  const int wr = w >> 1, wc = w & 1;
  const int lrow = lane & 15, lgrp = lane >> 4;

  // only Q-output tiles need the hi/lo emulated-fp32 path
  const bool useLo = SPLIT && !(EPI == 0 && bn >= 4);

  f32x4 acc[4][4] = {};

  auto stg = [&](int bf, int kt) {
    const int kk = kt << 5;
#pragma unroll
    for (int c = 0; c < 2; ++c) {
      const int i = tid + (c << 8);
      const int row = i >> 2;
      const int gch = ((i & 3) ^ ((i >> 3) & 3)) << 3;  // swizzled source chunk
      const size_t aoff = (size_t)(bm * 128 + row) * ks + hoff + kk + gch;
      const size_t boff = (size_t)(bnc * 128 + row) * ks + hoff + kk + gch;
      g2l16(Ah + aoff, &As[bf][0][i * 8]);
      g2l16(Bh + boff, &Bs[bf][0][i * 8]);
      if (SPLIT)
        if (useLo) {
          g2l16(Al + aoff, &As[bf][1][i * 8]);
          g2l16(Bl + boff, &Bs[bf][1][i * 8]);
        }
    }
  };

  auto compute = [&](int bf) {
    f16x8 a0[4], a1[4], b0[4], b1[4];
#pragma unroll
    for (int mf = 0; mf < 4; ++mf) {
      const int off = swz32(wr * 64 + mf * 16 + lrow, lgrp);
      a0[mf] = *(const f16x8*)&As[bf][0][off];
      if (SPLIT)
        if (useLo) a1[mf] = *(const f16x8*)&As[bf][SPLIT ? 1 : 0][off];
    }
#pragma unroll
    for (int nf = 0; nf < 4; ++nf) {
      const int off = swz32(wc * 64 + nf * 16 + lrow, lgrp);
      b0[nf] = *(const f16x8*)&Bs[bf][0][off];
      if (SPLIT)
        if (useLo) b1[nf] = *(const f16x8*)&Bs[bf][SPLIT ? 1 : 0][off];
    }
#pragma unroll
    for (int mf = 0; mf < 4; ++mf)
#pragma unroll
      for (int nf = 0; nf < 4; ++nf) {
        acc[mf][nf] = mfma16(a0[mf], b0[nf], acc[mf][nf]);
        if (SPLIT)
          if (useLo) {
            acc[mf][nf] = mfma16(a0[mf], b1[nf], acc[mf][nf]);
            acc[mf][nf] = mfma16(a1[mf], b0[nf], acc[mf][nf]);
          }
      }
  };

  const int nkt = K >> 5;
  stg(0, 0);
  __syncthreads();
  for (int kt = 0; kt < nkt; ++kt) {
    const int cur = kt & 1;
    if (kt + 1 < nkt) stg(cur ^ 1, kt + 1);  // overlaps compute below
    compute(cur);
    __syncthreads();  // drains this iter's stage (overlapped) + publishes buffer
  }

  const int rowbase = bm * 128 + wr * 64 + lgrp * 4;
  const int colbase = bnc * 128 + wc * 64 + lrow;
#pragma unroll
  for (int mf = 0; mf < 4; ++mf) {
#pragma unroll
    for (int nf = 0; nf < 4; ++nf) {
      const int gc = colbase + nf * 16;
      const float bv = (EPI == 3 && half) ? 0.f : bias[gc];
#pragma unroll
      for (int r = 0; r < 4; ++r) {
        const int gr = rowbase + mf * 16 + r;
        const float val = acc[mf][nf][r] + bv;
        if (EPI == 0) {
          const int bb = gr >> 11, tok = gr & 2047;
          const int kind = gc >> 9, hh = (gc >> 6) & 7, dd = gc & 63;
          const size_t bhp = (size_t)((bb << 3) + hh);
          const size_t qidx = (bhp * 2048 + tok) * 64 + dd;
          if (kind == 0) {
            const float sv = val * QK_SCALE;  // fold score scale + log2e into q
            const f16 hv = (f16)sv;
            oqh[qidx] = hv; oql[qidx] = (f16)(sv - (float)hv);
          } else if (kind == 1) {
            okh[qidx] = (f16)val;
          } else {
            ovT[(bhp * 64 + dd) * 2048 + tok] = (f16)val;
          }
        } else if (EPI == 1) {
          outH[(size_t)gr * N + gc] = (f16)fmaxf(val, 0.f);
        } else {
          f16* o = half ? outH2 : outH;
          o[(size_t)gr * N + gc] = (f16)val;
        }
      }
    }
  }
}

// ---------------- fused flash attention: 32x32 MFMA, in-reg softmax, T15 pipeline ----------
// (round-10 scheme: measured 67.6 us) 1D grid 512, XCD-aware bh-major swizzle.
// Block 256 = 4 waves; wave owns 32 q-rows. Two S-register sets: iteration t ISSUES
// QK(t+1) MFMAs, then softmax(t)+PV(t) run while they execute. K/V 4-buffer LDS
// pipeline (64 KB), stage distance 3, counted vmcnt(4). fp16 output.
__global__ __launch_bounds__(256, 2) void k_attn(
    const f16* __restrict__ Qh, const f16* __restrict__ Ql,
    const f16* __restrict__ Kh, const f16* __restrict__ Vt,
    f16* __restrict__ out) {
  __shared__ f16 sK[4][64 * 64], sV[4][64 * 64];

  const int tid = threadIdx.x;
  const int wg = (blockIdx.x & 7) * 64 + (blockIdx.x >> 3);
  const int bh = wg >> 4, qt = wg & 15;
  const int w = tid >> 6, lane = tid & 63;
  const int lh = lane & 31, hh = lane >> 5;

  // Q fragments first (their vmcnt resolves before the staging waits)
  const int qrow = qt * 128 + w * 32 + lh;
  const size_t qoff = ((size_t)bh * 2048 + qrow) * 64;
  f16x8 qh8[4], ql8[4];
#pragma unroll
  for (int d = 0; d < 4; ++d) {
    const size_t o = qoff + d * 16 + hh * 8;
    qh8[d] = *(const f16x8*)(Qh + o);
    ql8[d] = *(const f16x8*)(Ql + o);
  }

  auto stage = [&](int b, int kt) {
    const size_t koff = ((size_t)bh * 2048 + (size_t)kt * 64) * 64;
    const size_t voff = (size_t)bh * 64 * 2048 + (size_t)kt * 64;
#pragma unroll
    for (int c = 0; c < 2; ++c) {
      const int i = tid + (c << 8);
      const int row = i >> 3;
      const int gch = ((i & 7) ^ (row & 7)) << 3;
      g2l16(Kh + koff + (size_t)row * 64 + gch, &sK[b][i * 8]);
      g2l16(Vt + voff + (size_t)row * 2048 + gch, &sV[b][i * 8]);
    }
  };

  stage(0, 0);
  stage(1, 1);
  stage(2, 2);

  float m_run = -3e38f;
  float l_run = 0.f;
  f32x16 oacc[2] = {};
  const f32x16 kZero = {};
  f32x16 sA[2] = {}, sB[2] = {};

  // QK MFMA issue for one tile (buffer bi) into s[2]; first MFMA uses zero-C (no resets)
  auto qk = [&](f32x16 (&s)[2], int bi) {
    __builtin_amdgcn_s_setprio(1);
    {
      const f16x8 k0 = *(const f16x8*)&sK[bi][swz64(lh, hh)];
      const f16x8 k1 = *(const f16x8*)&sK[bi][swz64(32 + lh, hh)];
      s[0] = mfma32(k0, qh8[0], kZero);
      s[0] = mfma32(k0, ql8[0], s[0]);
      s[1] = mfma32(k1, qh8[0], kZero);
      s[1] = mfma32(k1, ql8[0], s[1]);
    }
#pragma unroll
    for (int d = 1; d < 4; ++d) {
      const f16x8 k0 = *(const f16x8*)&sK[bi][swz64(lh, d * 2 + hh)];
      const f16x8 k1 = *(const f16x8*)&sK[bi][swz64(32 + lh, d * 2 + hh)];
      s[0] = mfma32(k0, qh8[d], s[0]);
      s[0] = mfma32(k0, ql8[d], s[0]);
      s[1] = mfma32(k1, qh8[d], s[1]);
      s[1] = mfma32(k1, ql8[d], s[1]);
    }
    __builtin_amdgcn_s_setprio(0);
  };

  // softmax + PV for current tile (registers s, buffer bi)
  auto sm_pv = [&](f32x16 (&s)[2], int bi) {
    float mt = s[0][0];
#pragma unroll
    for (int r = 0; r < 16; ++r) { mt = fmaxf(mt, s[0][r]); mt = fmaxf(mt, s[1][r]); }
    mt = fmaxf(mt, __shfl_xor(mt, 32, 64));
    float mcur = m_run;
    if (!__all(mt <= mcur + 8.0f)) {  // defer-max
      const float mnew = fmaxf(mcur, mt);
      const float corr = __builtin_amdgcn_exp2f(mcur - mnew);
      m_run = mnew;
      l_run *= corr;
      oacc[0] = oacc[0] * corr;
      oacc[1] = oacc[1] * corr;
      mcur = mnew;
    }
    float ps = 0.f;
    unsigned pk0[8], pk1[8];
#pragma unroll
    for (int i = 0; i < 8; ++i) {
      const float a0 = __builtin_amdgcn_exp2f(s[0][2 * i] - mcur);
      const float a1 = __builtin_amdgcn_exp2f(s[0][2 * i + 1] - mcur);
      const float b0 = __builtin_amdgcn_exp2f(s[1][2 * i] - mcur);
      const float b1 = __builtin_amdgcn_exp2f(s[1][2 * i + 1] - mcur);
      ps += (a0 + a1) + (b0 + b1);
      pk0[i] = pkrtz(a0, a1);
      pk1[i] = pkrtz(b0, b1);
    }
    ps += __shfl_xor(ps, 32, 64);
    l_run += ps;

    swap32(pk0[0], pk0[2]); swap32(pk0[1], pk0[3]);
    swap32(pk0[4], pk0[6]); swap32(pk0[5], pk0[7]);
    swap32(pk1[0], pk1[2]); swap32(pk1[1], pk1[3]);
    swap32(pk1[4], pk1[6]); swap32(pk1[5], pk1[7]);

    u32x4 pbu[4];
    pbu[0] = (u32x4){pk0[0], pk0[1], pk0[2], pk0[3]};
    pbu[1] = (u32x4){pk0[4], pk0[5], pk0[6], pk0[7]};
    pbu[2] = (u32x4){pk1[0], pk1[1], pk1[2], pk1[3]};
    pbu[3] = (u32x4){pk1[4], pk1[5], pk1[6], pk1[7]};

    __builtin_amdgcn_s_setprio(1);
#pragma unroll
    for (int s2 = 0; s2 < 4; ++s2) {
      const f16x8 pb = *(const f16x8*)&pbu[s2];
#pragma unroll
      for (int db = 0; db < 2; ++db) {
        const f16x8 v = *(const f16x8*)&sV[bi][swz64(db * 32 + lh, s2 * 2 + hh)];
        oacc[db] = mfma32(v, pb, oacc[db]);
      }
    }
    __builtin_amdgcn_s_setprio(0);
  };

  auto endwait = [&](int t) {
    if (t < 29) {
      asm volatile("s_waitcnt vmcnt(4)" ::: "memory");
    } else {
      asm volatile("s_waitcnt vmcnt(0)" ::: "memory");
    }
    __builtin_amdgcn_sched_barrier(0);
    __builtin_amdgcn_s_barrier();
    __builtin_amdgcn_sched_barrier(0);
  };

  // prologue: wait stage(0),(1)
  asm volatile("s_waitcnt vmcnt(4)" ::: "memory");
  __builtin_amdgcn_sched_barrier(0);
  __builtin_amdgcn_s_barrier();
  __builtin_amdgcn_sched_barrier(0);
  qk(sA, 0);

  for (int t = 0; t < 32; t += 2) {
    {
      if (t + 1 < 32) qk(sB, (t + 1) & 3);
      if (t + 3 < 32) stage((t + 3) & 3, t + 3);
      sm_pv(sA, t & 3);
      if (t + 1 < 32) endwait(t);
    }
    if (t + 1 < 32) {
      if (t + 2 < 32) qk(sA, (t + 2) & 3);
      if (t + 4 < 32) stage((t + 4) & 3, t + 4);
      sm_pv(sB, (t + 1) & 3);
      if (t + 2 < 32) endwait(t + 1);
    }
  }

  const int b = bh >> 3, hd = bh & 7;
  const float inv = 1.0f / l_run;
  const int trow = b * 2048 + qt * 128 + w * 32 + lh;
  f16* po = out + (size_t)trow * 512 + hd * 64;
#pragma unroll
  for (int db = 0; db < 2; ++db)
#pragma unroll
    for (int rq = 0; rq < 4; ++rq) {
      f16x4 o;
#pragma unroll
      for (int j = 0; j < 4; ++j) o[j] = (f16)(oacc[db][rq * 4 + j] * inv);
      *(f16x4*)(po + db * 32 + rq * 8 + hh * 4) = o;
    }
}

// ---------------- LN1: y = LN(x + attn) -> fp16 only (4 rows/block, wave per row) ---------
__global__ __launch_bounds__(256) void k_ln1(const float* __restrict__ X, const f16* __restrict__ R,
                                             const float* __restrict__ g, const float* __restrict__ be,
                                             f16* __restrict__ outH) {
  const int row = blockIdx.x * 4 + (threadIdx.x >> 6);
  const int t = threadIdx.x & 63;
  const size_t base = (size_t)row * 512 + t * 8;
  f32x4 x0 = *(const f32x4*)(X + base);
  f32x4 x1 = *(const f32x4*)(X + base + 4);
  const f16x8 r = *(const f16x8*)(R + base);
#pragma unroll
  for (int j = 0; j < 4; ++j) { x0[j] += (float)r[j]; x1[j] += (float)r[j + 4]; }
  float s = 0.f, ss = 0.f;
#pragma unroll
  for (int j = 0; j < 4; ++j) { s += x0[j] + x1[j]; ss += x0[j] * x0[j] + x1[j] * x1[j]; }
#pragma unroll
  for (int o = 32; o; o >>= 1) {
    s += __shfl_xor(s, o, 64);
    ss += __shfl_xor(ss, o, 64);
  }
  const float mean = s * (1.f / 512.f);
  const float var = ss * (1.f / 512.f) - mean * mean;
  const float rs = rsqrtf(var + 1e-5f);
  f32x4 g0 = *(const f32x4*)(g + t * 8);
  f32x4 g1v = *(const f32x4*)(g + t * 8 + 4);
  f32x4 b0 = *(const f32x4*)(be + t * 8);
  f32x4 b1 = *(const f32x4*)(be + t * 8 + 4);
  f16x8 hx;
#pragma unroll
  for (int j = 0; j < 4; ++j) {
    hx[j] = (f16)((x0[j] - mean) * rs * g0[j] + b0[j]);
    hx[j + 4] = (f16)((x1[j] - mean) * rs * g1v[j] + b1[j]);
  }
  *(f16x8*)(outH + base) = hx;
}

// ---------------- LN2: y = LN(x1 + ff0 + ff1) -> fp32 out (ff partials fp16) --------------
__global__ __launch_bounds__(256) void k_ln2(const f16* __restrict__ Xh,
                                             const f16* __restrict__ R0, const f16* __restrict__ R1,
                                             const float* __restrict__ g, const float* __restrict__ be,
                                             float* __restrict__ out) {
  const int row = blockIdx.x * 4 + (threadIdx.x >> 6);
  const int t = threadIdx.x & 63;
  const size_t base = (size_t)row * 512 + t * 8;
  const f16x8 xv = *(const f16x8*)(Xh + base);
  const f16x8 r0 = *(const f16x8*)(R0 + base);
  const f16x8 r1 = *(const f16x8*)(R1 + base);
  f32x4 x0, x1;
#pragma unroll
  for (int j = 0; j < 4; ++j) {
    x0[j] = (float)xv[j] + (float)r0[j] + (float)r1[j];
    x1[j] = (float)xv[j + 4] + (float)r0[j + 4] + (float)r1[j + 4];
  }
  float s = 0.f, ss = 0.f;
#pragma unroll
  for (int j = 0; j < 4; ++j) { s += x0[j] + x1[j]; ss += x0[j] * x0[j] + x1[j] * x1[j]; }
#pragma unroll
  for (int o = 32; o; o >>= 1) {
    s += __shfl_xor(s, o, 64);
    ss += __shfl_xor(ss, o, 64);
  }
  const float mean = s * (1.f / 512.f);
  const float var = ss * (1.f / 512.f) - mean * mean;
  const float rs = rsqrtf(var + 1e-5f);
  f32x4 g0 = *(const f32x4*)(g + t * 8);
  f32x4 g1v = *(const f32x4*)(g + t * 8 + 4);
  f32x4 b0 = *(const f32x4*)(be + t * 8);
  f32x4 b1 = *(const f32x4*)(be + t * 8 + 4);
  f32x4 y0 = (x0 - mean) * rs * g0 + b0;
  f32x4 y1 = (x1 - mean) * rs * g1v + b1;
  *(f32x4*)(out + base) = y0;
  *(f32x4*)(out + base + 4) = y1;
}

extern "C" void kernel_launch(void* const* d_in, const int* in_sizes, int n_in,
                              void* d_out, int out_size, void* d_ws, size_t ws_size,
                              hipStream_t stream) {
  (void)in_sizes; (void)n_in; (void)out_size;
  const float* x = (const float*)d_in[0];
  const float* w_qkv = (const float*)d_in[1];
  const float* b_qkv = (const float*)d_in[2];
  const float* w1 = (const float*)d_in[3];
  const float* b1 = (const float*)d_in[4];
  const float* w2 = (const float*)d_in[5];
  const float* b2 = (const float*)d_in[6];
  const float* g1 = (const float*)d_in[7];
  const float* be1 = (const float*)d_in[8];
  const float* g2 = (const float*)d_in[9];
  const float* be2 = (const float*)d_in[10];
  float* out = (float*)d_out;

  char* p = (char*)d_ws;
  auto take = [&](size_t bytes) {
    char* r = p;
    p += (bytes + 255) & ~(size_t)255;
    return r;
  };
  f16* xh = (f16*)take(8192ull * 512 * 2);
  f16* xl = (f16*)take(8192ull * 512 * 2);
  f16* wqkvTh = (f16*)take(1536ull * 512 * 2);
  f16* wqkvTl = (f16*)take(1536ull * 512 * 2);
  f16* w1T = (f16*)take(2048ull * 512 * 2);
  f16* w2T = (f16*)take(512ull * 2048 * 2);
  f16* qh = (f16*)take(32ull * 2048 * 64 * 2);
  f16* ql = (f16*)take(32ull * 2048 * 64 * 2);
  f16* kh = (f16*)take(32ull * 2048 * 64 * 2);
  f16* vT = (f16*)take(32ull * 64 * 2048 * 2);
  f16* attnH = (f16*)take(8192ull * 512 * 2);
  f16* x1h = (f16*)take(8192ull * 512 * 2);
  f16* ffb0 = (f16*)take(8192ull * 512 * 2);
  f16* ffb1 = (f16*)take(8192ull * 512 * 2);
  // reuse: hbuf [8192][2048]f16 = 33.6MB spans qh,ql,kh,vT (all dead after attn)
  f16* hbuf = qh;

  if ((size_t)(p - (char*)d_ws) > ws_size) return;  // insufficient workspace -> loud validation fail

  dim3 tb(32, 8);
  k_split<<<4096, 256, 0, stream>>>(x, xh, xl, 8192 * 512 / 4);
  k_transpose_split<true><<<dim3(1536 / 32, 512 / 32), tb, 0, stream>>>(w_qkv, 512, 1536, wqkvTh, wqkvTl);
  k_transpose_split<false><<<dim3(2048 / 32, 512 / 32), tb, 0, stream>>>(w1, 512, 2048, w1T, nullptr);
  k_transpose_split<false><<<dim3(512 / 32, 2048 / 32), tb, 0, stream>>>(w2, 2048, 512, w2T, nullptr);

  k_gemm<0, true><<<dim3(64, 12), 256, 0, stream>>>(xh, xl, wqkvTh, wqkvTl, b_qkv,
                                                    nullptr, nullptr, qh, ql, kh, vT,
                                                    8192, 1536, 512, 512);
  k_attn<<<512, 256, 0, stream>>>(qh, ql, kh, vT, attnH);
  k_ln1<<<2048, 256, 0, stream>>>(x, attnH, g1, be1, x1h);
  k_gemm<1, false><<<dim3(64, 16), 256, 0, stream>>>(x1h, nullptr, w1T, nullptr, b1,
                                                     hbuf, nullptr, nullptr, nullptr, nullptr, nullptr,
                                                     8192, 2048, 512, 512);
  k_gemm<3, false><<<dim3(64, 8), 256, 0, stream>>>(hbuf, nullptr, w2T, nullptr, b2,
                                                    ffb0, ffb1, nullptr, nullptr, nullptr, nullptr,
                                                    8192, 512, 1024, 2048);
  k_ln2<<<2048, 256, 0, stream>>>(x1h, ffb0, ffb1, g2, be2, out);
}

// Round 13
// 186.158 us; speedup vs baseline: 1.0673x; 1.0226x over previous
//
#include <hip/hip_runtime.h>

typedef _Float16 f16;
typedef _Float16 f16x4 __attribute__((ext_vector_type(4)));
typedef _Float16 f16x8 __attribute__((ext_vector_type(8)));
typedef float    f32x4 __attribute__((ext_vector_type(4)));
typedef float    f32x16 __attribute__((ext_vector_type(16)));
typedef unsigned int u32x4 __attribute__((ext_vector_type(4)));

#define QK_SCALE 11.5416528f  // 8 * log2(e): scores pre-scaled into exp2 domain

__device__ __forceinline__ void g2l16(const void* g, void* l) {
  __builtin_amdgcn_global_load_lds(
      (__attribute__((address_space(1))) const unsigned int*)g,
      (__attribute__((address_space(3))) unsigned int*)l, 16, 0, 0);
}

__device__ __forceinline__ f32x4 mfma16(f16x8 a, f16x8 b, f32x4 c) {
  return __builtin_amdgcn_mfma_f32_16x16x32_f16(a, b, c, 0, 0, 0);
}
__device__ __forceinline__ f32x16 mfma32(f16x8 a, f16x8 b, f32x16 c) {
  return __builtin_amdgcn_mfma_f32_32x32x16_f16(a, b, c, 0, 0, 0);
}
__device__ __forceinline__ unsigned pkrtz(float a, float b) {
  auto t = __builtin_amdgcn_cvt_pkrtz(a, b);  // __fp16 ext_vector_type(2)
  return *(unsigned*)&t;
}
// v_permlane32_swap_b32: a.upper32lanes <-> b.lower32lanes (modifies both)
__device__ __forceinline__ void swap32(unsigned& a, unsigned& b) {
  asm volatile("v_permlane32_swap_b32 %0, %1" : "+v"(a), "+v"(b));
}

// Used ONLY in attn (m141: sched_barrier pinning poisons GEMM loops).
#define WAIT_BARRIER(N)                                        \
  do {                                                         \
    asm volatile("s_waitcnt vmcnt(" #N ")" ::: "memory");      \
    __builtin_amdgcn_sched_barrier(0);                         \
    __builtin_amdgcn_s_barrier();                              \
    __builtin_amdgcn_sched_barrier(0);                         \
  } while (0)

// XOR-swizzled LDS offsets (f16 units). Rows of 64 f16 (8x16B chunks) / 32 f16 (4x16B chunks).
__device__ __forceinline__ int swz64(int row, int c) { return row * 64 + ((c ^ (row & 7)) << 3); }
__device__ __forceinline__ int swz32(int row, int c) { return row * 32 + ((c ^ ((row >> 1) & 3)) << 3); }

// ---------------- fp32 -> fp16 hi/lo split (vectorized) ----------------
__global__ __launch_bounds__(256) void k_split(const float* __restrict__ in,
                                               f16* __restrict__ hi, f16* __restrict__ lo, int n4) {
  int i = blockIdx.x * 256 + threadIdx.x;
  if (i >= n4) return;
  f32x4 v = ((const f32x4*)in)[i];
  f16x4 h, l;
#pragma unroll
  for (int j = 0; j < 4; ++j) {
    f16 hv = (f16)v[j];
    h[j] = hv;
    l[j] = (f16)(v[j] - (float)hv);
  }
  ((f16x4*)hi)[i] = h;
  ((f16x4*)lo)[i] = l;
}

// ---------------- transpose fp32 [K][N] -> fp16 [N][K] (hi, optional lo) ----------------
template <bool WLO>
__global__ __launch_bounds__(256) void k_transpose_split(const float* __restrict__ in, int K, int N,
                                                         f16* __restrict__ oh, f16* __restrict__ ol) {
  __shared__ float t[32][33];
  const int tx = threadIdx.x, ty = threadIdx.y;
  const int n0 = blockIdx.x * 32, k0 = blockIdx.y * 32;
#pragma unroll
  for (int j = 0; j < 4; ++j)
    t[ty + j * 8][tx] = in[(size_t)(k0 + ty + j * 8) * N + n0 + tx];
  __syncthreads();
#pragma unroll
  for (int j = 0; j < 4; ++j) {
    float v = t[tx][ty + j * 8];
    f16 hv = (f16)v;
    size_t o = (size_t)(n0 + ty + j * 8) * K + k0 + tx;
    oh[o] = hv;
    if (WLO) ol[o] = (f16)(v - (float)hv);
  }
}

// ---------------- GEMM (R10-measured config): C = A*B, B transposed [N][K+] --------------
// Serial single-buffer staging (measured best at these shapes). ks = row stride.
// EPI 0: qkv scatter; Q tiles (bn<4) 3-term split; K,V tiles 1-term
// EPI 1: relu -> fp16 out
// EPI 3: split-K pair: bn>>2 = K-half; fp32 partials to outF (half0, +bias) / outF2 (half1)
template <int EPI, bool SPLIT>
__global__ __launch_bounds__(256, SPLIT ? 2 : 3) void k_gemm(
    const f16* __restrict__ Ah, const f16* __restrict__ Al,
    const f16* __restrict__ Bh, const f16* __restrict__ Bl,
    const float* __restrict__ bias,
    float* __restrict__ outF, float* __restrict__ outF2, f16* __restrict__ outH,
    f16* __restrict__ oqh, f16* __restrict__ oql,
    f16* __restrict__ okh, f16* __restrict__ ovT,
    int M, int N, int K, int ks) {
  constexpr int NB = SPLIT ? 2 : 1;
  __shared__ f16 As[NB][128 * 32];
  __shared__ f16 Bs[NB][128 * 32];

  const int tid = threadIdx.x;
  const int bm = blockIdx.x, bn = blockIdx.y;
  const int bnc = (EPI == 3) ? (bn & 3) : bn;
  const int half = (EPI == 3) ? (bn >> 2) : 0;
  const int hoff = half * 1024;
  const int w = tid >> 6, lane = tid & 63;
  const int wr = w >> 1, wc = w & 1;
  const int lrow = lane & 15, lgrp = lane >> 4;

  // only Q-output tiles need the hi/lo emulated-fp32 path
  const bool useLo = SPLIT && !(EPI == 0 && bn >= 4);

  f32x4 acc[4][4] = {};

  const int nkt = K >> 5;
  for (int kt = 0; kt < nkt; ++kt) {
    __syncthreads();
    const int kk = kt << 5;
#pragma unroll
    for (int c = 0; c < 2; ++c) {
      const int i = tid + (c << 8);
      const int row = i >> 2;
      const int gch = ((i & 3) ^ ((i >> 3) & 3)) << 3;  // swizzled source chunk
      const size_t aoff = (size_t)(bm * 128 + row) * ks + hoff + kk + gch;
      const size_t boff = (size_t)(bnc * 128 + row) * ks + hoff + kk + gch;
      g2l16(Ah + aoff, &As[0][i * 8]);
      g2l16(Bh + boff, &Bs[0][i * 8]);
      if (SPLIT)
        if (useLo) {
          g2l16(Al + aoff, &As[1][i * 8]);
          g2l16(Bl + boff, &Bs[1][i * 8]);
        }
    }
    __syncthreads();

    f16x8 a0[4], a1[4], b0[4], b1[4];
#pragma unroll
    for (int mf = 0; mf < 4; ++mf) {
      const int off = swz32(wr * 64 + mf * 16 + lrow, lgrp);
      a0[mf] = *(const f16x8*)&As[0][off];
      if (SPLIT)
        if (useLo) a1[mf] = *(const f16x8*)&As[SPLIT ? 1 : 0][off];
    }
#pragma unroll
    for (int nf = 0; nf < 4; ++nf) {
      const int off = swz32(wc * 64 + nf * 16 + lrow, lgrp);
      b0[nf] = *(const f16x8*)&Bs[0][off];
      if (SPLIT)
        if (useLo) b1[nf] = *(const f16x8*)&Bs[SPLIT ? 1 : 0][off];
    }
#pragma unroll
    for (int mf = 0; mf < 4; ++mf)
#pragma unroll
      for (int nf = 0; nf < 4; ++nf) {
        acc[mf][nf] = mfma16(a0[mf], b0[nf], acc[mf][nf]);
        if (SPLIT)
          if (useLo) {
            acc[mf][nf] = mfma16(a0[mf], b1[nf], acc[mf][nf]);
            acc[mf][nf] = mfma16(a1[mf], b0[nf], acc[mf][nf]);
          }
      }
  }

  const int rowbase = bm * 128 + wr * 64 + lgrp * 4;
  const int colbase = bnc * 128 + wc * 64 + lrow;
#pragma unroll
  for (int mf = 0; mf < 4; ++mf) {
#pragma unroll
    for (int nf = 0; nf < 4; ++nf) {
      const int gc = colbase + nf * 16;
      const float bv = (EPI == 3 && half) ? 0.f : bias[gc];
#pragma unroll
      for (int r = 0; r < 4; ++r) {
        const int gr = rowbase + mf * 16 + r;
        const float val = acc[mf][nf][r] + bv;
        if (EPI == 0) {
          const int bb = gr >> 11, tok = gr & 2047;
          const int kind = gc >> 9, hh = (gc >> 6) & 7, dd = gc & 63;
          const size_t bhp = (size_t)((bb << 3) + hh);
          const size_t qidx = (bhp * 2048 + tok) * 64 + dd;
          if (kind == 0) {
            const float sv = val * QK_SCALE;  // fold score scale + log2e into q
            const f16 hv = (f16)sv;
            oqh[qidx] = hv; oql[qidx] = (f16)(sv - (float)hv);
          } else if (kind == 1) {
            okh[qidx] = (f16)val;
          } else {
            ovT[(bhp * 64 + dd) * 2048 + tok] = (f16)val;
          }
        } else if (EPI == 1) {
          outH[(size_t)gr * N + gc] = (f16)fmaxf(val, 0.f);
        } else {
          float* o = half ? outF2 : outF;
          o[(size_t)gr * N + gc] = val;
        }
      }
    }
  }
}

// ---------------- fused flash attention: split-KV 2-way, 32x32 MFMA, in-reg softmax -------
// grid 1024 (16 qt x 32 bh x 2 kv-halves), XCD-aware bh-major swizzle; block 256 = 4 waves;
// wave owns 32 q-rows x 1024 keys (16 tiles). 2-buffer LDS dbuf (32 KB) -> 4 blocks/CU.
// Emits locally-normalized O (fp16) + per-row (m,l); k_merge combines the halves.
__global__ __launch_bounds__(256, 4) void k_attn(
    const f16* __restrict__ Qh, const f16* __restrict__ Ql,
    const f16* __restrict__ Kh, const f16* __restrict__ Vt,
    f16* __restrict__ opart, float2* __restrict__ ml) {
  __shared__ f16 sK[2][64 * 64], sV[2][64 * 64];

  const int tid = threadIdx.x;
  const int wg = ((blockIdx.x & 7) << 7) + (blockIdx.x >> 3);  // XCD x -> bh in [4x,4x+4)
  const int bh = wg >> 5;
  const int qt = (wg & 31) >> 1;
  const int half = wg & 1;
  const int w = tid >> 6, lane = tid & 63;
  const int lh = lane & 31, hh = lane >> 5;

  // Q fragments (32 rows for this wave) straight from global into registers.
  const int qrow = qt * 128 + w * 32 + lh;
  const size_t qoff = ((size_t)bh * 2048 + qrow) * 64;
  f16x8 qh8[4], ql8[4];
#pragma unroll
  for (int d = 0; d < 4; ++d) {
    const size_t o = qoff + d * 16 + hh * 8;
    qh8[d] = *(const f16x8*)(Qh + o);
    ql8[d] = *(const f16x8*)(Ql + o);
  }

  const int kt0 = half * 16;  // this block's kv-tile range [kt0, kt0+16)
  auto stage = [&](int b, int kt) {
    const size_t koff = ((size_t)bh * 2048 + (size_t)(kt0 + kt) * 64) * 64;
    const size_t voff = (size_t)bh * 64 * 2048 + (size_t)(kt0 + kt) * 64;
#pragma unroll
    for (int c = 0; c < 2; ++c) {
      const int i = tid + (c << 8);
      const int row = i >> 3;
      const int gch = ((i & 7) ^ (row & 7)) << 3;
      g2l16(Kh + koff + (size_t)row * 64 + gch, &sK[b][i * 8]);
      g2l16(Vt + voff + (size_t)row * 2048 + gch, &sV[b][i * 8]);
    }
  };

  float m_run = -3e38f;
  float l_run = 0.f;
  f32x16 oacc[2] = {};
  const f32x16 kZero = {};
  f32x16 s[2];

  auto qk = [&](int bi) {
    __builtin_amdgcn_s_setprio(1);
    {
      const f16x8 k0 = *(const f16x8*)&sK[bi][swz64(lh, hh)];
      const f16x8 k1 = *(const f16x8*)&sK[bi][swz64(32 + lh, hh)];
      s[0] = mfma32(k0, qh8[0], kZero);
      s[0] = mfma32(k0, ql8[0], s[0]);
      s[1] = mfma32(k1, qh8[0], kZero);
      s[1] = mfma32(k1, ql8[0], s[1]);
    }
#pragma unroll
    for (int d = 1; d < 4; ++d) {
      const f16x8 k0 = *(const f16x8*)&sK[bi][swz64(lh, d * 2 + hh)];
      const f16x8 k1 = *(const f16x8*)&sK[bi][swz64(32 + lh, d * 2 + hh)];
      s[0] = mfma32(k0, qh8[d], s[0]);
      s[0] = mfma32(k0, ql8[d], s[0]);
      s[1] = mfma32(k1, qh8[d], s[1]);
      s[1] = mfma32(k1, ql8[d], s[1]);
    }
    __builtin_amdgcn_s_setprio(0);
  };

  auto sm_pv = [&](int bi) {
    float mt = s[0][0];
#pragma unroll
    for (int r = 0; r < 16; ++r) { mt = fmaxf(mt, s[0][r]); mt = fmaxf(mt, s[1][r]); }
    mt = fmaxf(mt, __shfl_xor(mt, 32, 64));
    float mcur = m_run;
    if (!__all(mt <= mcur + 8.0f)) {  // defer-max
      const float mnew = fmaxf(mcur, mt);
      const float corr = __builtin_amdgcn_exp2f(mcur - mnew);
      m_run = mnew;
      l_run *= corr;
      oacc[0] = oacc[0] * corr;
      oacc[1] = oacc[1] * corr;
      mcur = mnew;
    }
    float ps = 0.f;
    unsigned pk0[8], pk1[8];
#pragma unroll
    for (int i = 0; i < 8; ++i) {
      const float a0 = __builtin_amdgcn_exp2f(s[0][2 * i] - mcur);
      const float a1 = __builtin_amdgcn_exp2f(s[0][2 * i + 1] - mcur);
      const float b0 = __builtin_amdgcn_exp2f(s[1][2 * i] - mcur);
      const float b1 = __builtin_amdgcn_exp2f(s[1][2 * i + 1] - mcur);
      ps += (a0 + a1) + (b0 + b1);
      pk0[i] = pkrtz(a0, a1);
      pk1[i] = pkrtz(b0, b1);
    }
    ps += __shfl_xor(ps, 32, 64);
    l_run += ps;

    swap32(pk0[0], pk0[2]); swap32(pk0[1], pk0[3]);
    swap32(pk0[4], pk0[6]); swap32(pk0[5], pk0[7]);
    swap32(pk1[0], pk1[2]); swap32(pk1[1], pk1[3]);
    swap32(pk1[4], pk1[6]); swap32(pk1[5], pk1[7]);

    u32x4 pbu[4];
    pbu[0] = (u32x4){pk0[0], pk0[1], pk0[2], pk0[3]};
    pbu[1] = (u32x4){pk0[4], pk0[5], pk0[6], pk0[7]};
    pbu[2] = (u32x4){pk1[0], pk1[1], pk1[2], pk1[3]};
    pbu[3] = (u32x4){pk1[4], pk1[5], pk1[6], pk1[7]};

    __builtin_amdgcn_s_setprio(1);
#pragma unroll
    for (int s2 = 0; s2 < 4; ++s2) {
      const f16x8 pb = *(const f16x8*)&pbu[s2];
#pragma unroll
      for (int db = 0; db < 2; ++db) {
        const f16x8 v = *(const f16x8*)&sV[bi][swz64(db * 32 + lh, s2 * 2 + hh)];
        oacc[db] = mfma32(v, pb, oacc[db]);
      }
    }
    __builtin_amdgcn_s_setprio(0);
  };

  stage(0, 0);
  WAIT_BARRIER(0);  // Q loads + tile 0 drained, published

  for (int kt = 0; kt < 16; ++kt) {
    const int cur = kt & 1;
    if (kt + 1 < 16) stage(cur ^ 1, kt + 1);  // lands under qk+sm_pv below
    qk(cur);
    sm_pv(cur);
    if (kt + 1 < 16) WAIT_BARRIER(0);
  }

  // locally-normalized partial O (fp16) + (m,l) per q-row
  const float inv = 1.0f / l_run;
  const int trow_l = qt * 128 + w * 32 + lh;
  const size_t pbase = ((size_t)(half * 32 + bh) * 2048 + trow_l) * 64;
#pragma unroll
  for (int db = 0; db < 2; ++db)
#pragma unroll
    for (int rq = 0; rq < 4; ++rq) {
      f16x4 o;
#pragma unroll
      for (int j = 0; j < 4; ++j) o[j] = (f16)(oacc[db][rq * 4 + j] * inv);
      *(f16x4*)(opart + pbase + db * 32 + rq * 8 + hh * 4) = o;
    }
  if (hh == 0)
    ml[(size_t)(half * 32 + bh) * 2048 + trow_l] = make_float2(m_run, l_run);
}

// ---------------- merge the two kv-halves: O = (w0*O0 + w1*O1)/(w0+w1) -------------------
__global__ __launch_bounds__(256) void k_merge(const f16* __restrict__ opart,
                                               const float2* __restrict__ ml,
                                               f16* __restrict__ out) {
  const int t = blockIdx.x * 256 + threadIdx.x;
  const int base = t * 8;                 // elem offset in [0, 8192*512)
  const int trow = base >> 9;
  const int c0 = base & 511;
  const int b = trow >> 11, tl = trow & 2047;
  const int hd = c0 >> 6, d0 = c0 & 63;
  const int bh = b * 8 + hd;
  const size_t i0 = ((size_t)bh * 2048 + tl) * 64 + d0;
  const size_t i1 = ((size_t)(32 + bh) * 2048 + tl) * 64 + d0;
  const f16x8 o0 = *(const f16x8*)(opart + i0);
  const f16x8 o1 = *(const f16x8*)(opart + i1);
  const float2 ml0 = ml[(size_t)bh * 2048 + tl];
  const float2 ml1 = ml[(size_t)(32 + bh) * 2048 + tl];
  const float M = fmaxf(ml0.x, ml1.x);
  const float w0 = ml0.y * __builtin_amdgcn_exp2f(ml0.x - M);
  const float w1 = ml1.y * __builtin_amdgcn_exp2f(ml1.x - M);
  const float inv = 1.f / (w0 + w1);
  const float c0f = w0 * inv, c1f = w1 * inv;
  f16x8 r;
#pragma unroll
  for (int j = 0; j < 8; ++j) r[j] = (f16)(c0f * (float)o0[j] + c1f * (float)o1[j]);
  *(f16x8*)(out + (size_t)trow * 512 + c0) = r;
}

// ---------------- LN1: y = LN(x + attn) -> fp16 only (4 rows/block, wave per row) ---------
__global__ __launch_bounds__(256) void k_ln1(const float* __restrict__ X, const f16* __restrict__ R,
                                             const float* __restrict__ g, const float* __restrict__ be,
                                             f16* __restrict__ outH) {
  const int row = blockIdx.x * 4 + (threadIdx.x >> 6);
  const int t = threadIdx.x & 63;
  const size_t base = (size_t)row * 512 + t * 8;
  f32x4 x0 = *(const f32x4*)(X + base);
  f32x4 x1 = *(const f32x4*)(X + base + 4);
  const f16x8 r = *(const f16x8*)(R + base);
#pragma unroll
  for (int j = 0; j < 4; ++j) { x0[j] += (float)r[j]; x1[j] += (float)r[j + 4]; }
  float s = 0.f, ss = 0.f;
#pragma unroll
  for (int j = 0; j < 4; ++j) { s += x0[j] + x1[j]; ss += x0[j] * x0[j] + x1[j] * x1[j]; }
#pragma unroll
  for (int o = 32; o; o >>= 1) {
    s += __shfl_xor(s, o, 64);
    ss += __shfl_xor(ss, o, 64);
  }
  const float mean = s * (1.f / 512.f);
  const float var = ss * (1.f / 512.f) - mean * mean;
  const float rs = rsqrtf(var + 1e-5f);
  f32x4 g0 = *(const f32x4*)(g + t * 8);
  f32x4 g1v = *(const f32x4*)(g + t * 8 + 4);
  f32x4 b0 = *(const f32x4*)(be + t * 8);
  f32x4 b1 = *(const f32x4*)(be + t * 8 + 4);
  f16x8 hx;
#pragma unroll
  for (int j = 0; j < 4; ++j) {
    hx[j] = (f16)((x0[j] - mean) * rs * g0[j] + b0[j]);
    hx[j + 4] = (f16)((x1[j] - mean) * rs * g1v[j] + b1[j]);
  }
  *(f16x8*)(outH + base) = hx;
}

// ---------------- LN2: y = LN(x1 + ff0 + ff1) -> fp32 out (fp32 partials, R10 config) -----
__global__ __launch_bounds__(256) void k_ln2(const f16* __restrict__ Xh,
                                             const float* __restrict__ R0, const float* __restrict__ R1,
                                             const float* __restrict__ g, const float* __restrict__ be,
                                             float* __restrict__ out) {
  const int row = blockIdx.x * 4 + (threadIdx.x >> 6);
  const int t = threadIdx.x & 63;
  const size_t base = (size_t)row * 512 + t * 8;
  const f16x8 xv = *(const f16x8*)(Xh + base);
  f32x4 r00 = *(const f32x4*)(R0 + base);
  f32x4 r01 = *(const f32x4*)(R0 + base + 4);
  f32x4 r10 = *(const f32x4*)(R1 + base);
  f32x4 r11 = *(const f32x4*)(R1 + base + 4);
  f32x4 x0, x1;
#pragma unroll
  for (int j = 0; j < 4; ++j) {
    x0[j] = (float)xv[j] + r00[j] + r10[j];
    x1[j] = (float)xv[j + 4] + r01[j] + r11[j];
  }
  float s = 0.f, ss = 0.f;
#pragma unroll
  for (int j = 0; j < 4; ++j) { s += x0[j] + x1[j]; ss += x0[j] * x0[j] + x1[j] * x1[j]; }
#pragma unroll
  for (int o = 32; o; o >>= 1) {
    s += __shfl_xor(s, o, 64);
    ss += __shfl_xor(ss, o, 64);
  }
  const float mean = s * (1.f / 512.f);
  const float var = ss * (1.f / 512.f) - mean * mean;
  const float rs = rsqrtf(var + 1e-5f);
  f32x4 g0 = *(const f32x4*)(g + t * 8);
  f32x4 g1v = *(const f32x4*)(g + t * 8 + 4);
  f32x4 b0 = *(const f32x4*)(be + t * 8);
  f32x4 b1 = *(const f32x4*)(be + t * 8 + 4);
  f32x4 y0 = (x0 - mean) * rs * g0 + b0;
  f32x4 y1 = (x1 - mean) * rs * g1v + b1;
  *(f32x4*)(out + base) = y0;
  *(f32x4*)(out + base + 4) = y1;
}

extern "C" void kernel_launch(void* const* d_in, const int* in_sizes, int n_in,
                              void* d_out, int out_size, void* d_ws, size_t ws_size,
                              hipStream_t stream) {
  (void)in_sizes; (void)n_in; (void)out_size;
  const float* x = (const float*)d_in[0];
  const float* w_qkv = (const float*)d_in[1];
  const float* b_qkv = (const float*)d_in[2];
  const float* w1 = (const float*)d_in[3];
  const float* b1 = (const float*)d_in[4];
  const float* w2 = (const float*)d_in[5];
  const float* b2 = (const float*)d_in[6];
  const float* g1 = (const float*)d_in[7];
  const float* be1 = (const float*)d_in[8];
  const float* g2 = (const float*)d_in[9];
  const float* be2 = (const float*)d_in[10];
  float* out = (float*)d_out;

  char* p = (char*)d_ws;
  auto take = [&](size_t bytes) {
    char* r = p;
    p += (bytes + 255) & ~(size_t)255;
    return r;
  };
  f16* xh = (f16*)take(8192ull * 512 * 2);
  f16* xl = (f16*)take(8192ull * 512 * 2);
  f16* wqkvTh = (f16*)take(1536ull * 512 * 2);
  f16* wqkvTl = (f16*)take(1536ull * 512 * 2);
  f16* w1T = (f16*)take(2048ull * 512 * 2);
  f16* w2T = (f16*)take(512ull * 2048 * 2);
  f16* qh = (f16*)take(32ull * 2048 * 64 * 2);
  f16* ql = (f16*)take(32ull * 2048 * 64 * 2);
  f16* kh = (f16*)take(32ull * 2048 * 64 * 2);
  f16* vT = (f16*)take(32ull * 64 * 2048 * 2);
  f16* attnH = (f16*)take(8192ull * 512 * 2);
  f16* x1h = (f16*)take(8192ull * 512 * 2);
  float* ffb0 = (float*)take(8192ull * 512 * 4);
  float* ffb1 = (float*)take(8192ull * 512 * 4);
  float* mlb = (float*)take(2ull * 32 * 2048 * 8);
  // reuse: hbuf spans qh..vT (dead after attn); opart overlays ffb0 (16.78MB, written by
  // attn, consumed by merge BEFORE ff2 writes ffb0)
  f16* hbuf = qh;
  f16* opart = (f16*)ffb0;

  if ((size_t)(p - (char*)d_ws) > ws_size) return;  // insufficient workspace -> loud validation fail

  dim3 tb(32, 8);
  k_split<<<4096, 256, 0, stream>>>(x, xh, xl, 8192 * 512 / 4);
  k_transpose_split<true><<<dim3(1536 / 32, 512 / 32), tb, 0, stream>>>(w_qkv, 512, 1536, wqkvTh, wqkvTl);
  k_transpose_split<false><<<dim3(2048 / 32, 512 / 32), tb, 0, stream>>>(w1, 512, 2048, w1T, nullptr);
  k_transpose_split<false><<<dim3(512 / 32, 2048 / 32), tb, 0, stream>>>(w2, 2048, 512, w2T, nullptr);

  k_gemm<0, true><<<dim3(64, 12), 256, 0, stream>>>(xh, xl, wqkvTh, wqkvTl, b_qkv,
                                                    nullptr, nullptr, nullptr, qh, ql, kh, vT,
                                                    8192, 1536, 512, 512);
  k_attn<<<1024, 256, 0, stream>>>(qh, ql, kh, vT, opart, (float2*)mlb);
  k_merge<<<2048, 256, 0, stream>>>(opart, (const float2*)mlb, attnH);
  k_ln1<<<2048, 256, 0, stream>>>(x, attnH, g1, be1, x1h);
  k_gemm<1, false><<<dim3(64, 16), 256, 0, stream>>>(x1h, nullptr, w1T, nullptr, b1,
                                                     nullptr, nullptr, hbuf, nullptr, nullptr, nullptr, nullptr,
                                                     8192, 2048, 512, 512);
  k_gemm<3, false><<<dim3(64, 8), 256, 0, stream>>>(hbuf, nullptr, w2T, nullptr, b2,
                                                    ffb0, ffb1, nullptr, nullptr, nullptr, nullptr, nullptr,
                                                    8192, 512, 1024, 2048);
  k_ln2<<<2048, 256, 0, stream>>>(x1h, ffb0, ffb1, g2, be2, out);
}

// Round 14
// 180.994 us; speedup vs baseline: 1.0977x; 1.0285x over previous
//
#include <hip/hip_runtime.h>

typedef _Float16 f16;
typedef _Float16 f16x4 __attribute__((ext_vector_type(4)));
typedef _Float16 f16x8 __attribute__((ext_vector_type(8)));
typedef float    f32x4 __attribute__((ext_vector_type(4)));
typedef float    f32x16 __attribute__((ext_vector_type(16)));
typedef unsigned int u32x4 __attribute__((ext_vector_type(4)));

#define QK_SCALE 11.5416528f  // 8 * log2(e): scores pre-scaled into exp2 domain

__device__ __forceinline__ void g2l16(const void* g, void* l) {
  __builtin_amdgcn_global_load_lds(
      (__attribute__((address_space(1))) const unsigned int*)g,
      (__attribute__((address_space(3))) unsigned int*)l, 16, 0, 0);
}

__device__ __forceinline__ f32x4 mfma16(f16x8 a, f16x8 b, f32x4 c) {
  return __builtin_amdgcn_mfma_f32_16x16x32_f16(a, b, c, 0, 0, 0);
}
__device__ __forceinline__ f32x16 mfma32(f16x8 a, f16x8 b, f32x16 c) {
  return __builtin_amdgcn_mfma_f32_32x32x16_f16(a, b, c, 0, 0, 0);
}
__device__ __forceinline__ unsigned pkrtz(float a, float b) {
  auto t = __builtin_amdgcn_cvt_pkrtz(a, b);  // __fp16 ext_vector_type(2)
  return *(unsigned*)&t;
}
// v_permlane32_swap_b32: a.upper32lanes <-> b.lower32lanes (modifies both)
__device__ __forceinline__ void swap32(unsigned& a, unsigned& b) {
  asm volatile("v_permlane32_swap_b32 %0, %1" : "+v"(a), "+v"(b));
}

// Used ONLY in attn (m141: sched_barrier pinning poisons GEMM loops).
#define WAIT_BARRIER(N)                                        \
  do {                                                         \
    asm volatile("s_waitcnt vmcnt(" #N ")" ::: "memory");      \
    __builtin_amdgcn_sched_barrier(0);                         \
    __builtin_amdgcn_s_barrier();                              \
    __builtin_amdgcn_sched_barrier(0);                         \
  } while (0)

// XOR-swizzled LDS offsets (f16 units). Rows of 64 f16 (8x16B chunks) / 32 f16 (4x16B chunks).
__device__ __forceinline__ int swz64(int row, int c) { return row * 64 + ((c ^ (row & 7)) << 3); }
__device__ __forceinline__ int swz32(int row, int c) { return row * 32 + ((c ^ ((row >> 1) & 3)) << 3); }

// ---------------- fp32 -> fp16 hi/lo split (vectorized) ----------------
__global__ __launch_bounds__(256) void k_split(const float* __restrict__ in,
                                               f16* __restrict__ hi, f16* __restrict__ lo, int n4) {
  int i = blockIdx.x * 256 + threadIdx.x;
  if (i >= n4) return;
  f32x4 v = ((const f32x4*)in)[i];
  f16x4 h, l;
#pragma unroll
  for (int j = 0; j < 4; ++j) {
    f16 hv = (f16)v[j];
    h[j] = hv;
    l[j] = (f16)(v[j] - (float)hv);
  }
  ((f16x4*)hi)[i] = h;
  ((f16x4*)lo)[i] = l;
}

// ---------------- transpose fp32 [K][N] -> fp16 [N][K] (hi, optional lo) ----------------
template <bool WLO>
__global__ __launch_bounds__(256) void k_transpose_split(const float* __restrict__ in, int K, int N,
                                                         f16* __restrict__ oh, f16* __restrict__ ol) {
  __shared__ float t[32][33];
  const int tx = threadIdx.x, ty = threadIdx.y;
  const int n0 = blockIdx.x * 32, k0 = blockIdx.y * 32;
#pragma unroll
  for (int j = 0; j < 4; ++j)
    t[ty + j * 8][tx] = in[(size_t)(k0 + ty + j * 8) * N + n0 + tx];
  __syncthreads();
#pragma unroll
  for (int j = 0; j < 4; ++j) {
    float v = t[tx][ty + j * 8];
    f16 hv = (f16)v;
    size_t o = (size_t)(n0 + ty + j * 8) * K + k0 + tx;
    oh[o] = hv;
    if (WLO) ol[o] = (f16)(v - (float)hv);
  }
}

// ---------------- GEMM (R10 config + XCD-chunked bm-major swizzle) -----------------------
// 1D grid = NBM*NBN, nwg%8==0. Logical id wg is bm-major (bn fastest); the swizzle
// wg=(bid%8)*cpx+bid/8 gives each XCD a CONTIGUOUS logical chunk -> the NBN blocks
// sharing an A row-panel are co-resident on one XCD -> A read once from HBM, reuse from L2.
// EPI 0: qkv scatter; Q tiles (bn<4) 3-term split; K,V tiles 1-term
// EPI 1: relu -> fp16 out
// EPI 3: split-K pair: bn>>2 = K-half; fp32 partials to outF (half0, +bias) / outF2 (half1)
template <int EPI, bool SPLIT>
__global__ __launch_bounds__(256, SPLIT ? 2 : 3) void k_gemm(
    const f16* __restrict__ Ah, const f16* __restrict__ Al,
    const f16* __restrict__ Bh, const f16* __restrict__ Bl,
    const float* __restrict__ bias,
    float* __restrict__ outF, float* __restrict__ outF2, f16* __restrict__ outH,
    f16* __restrict__ oqh, f16* __restrict__ oql,
    f16* __restrict__ okh, f16* __restrict__ ovT,
    int M, int N, int K, int ks, int nbn) {
  constexpr int NB = SPLIT ? 2 : 1;
  __shared__ f16 As[NB][128 * 32];
  __shared__ f16 Bs[NB][128 * 32];

  const int tid = threadIdx.x;
  const int cpx = gridDim.x >> 3;
  const int wg = (blockIdx.x & 7) * cpx + (blockIdx.x >> 3);
  const int bm = wg / nbn;
  const int bn = wg - bm * nbn;
  const int bnc = (EPI == 3) ? (bn & 3) : bn;
  const int half = (EPI == 3) ? (bn >> 2) : 0;
  const int hoff = half * 1024;
  const int w = tid >> 6, lane = tid & 63;
  const int wr = w >> 1, wc = w & 1;
  const int lrow = lane & 15, lgrp = lane >> 4;

  // only Q-output tiles need the hi/lo emulated-fp32 path
  const bool useLo = SPLIT && !(EPI == 0 && bn >= 4);

  f32x4 acc[4][4] = {};

  const int nkt = K >> 5;
  for (int kt = 0; kt < nkt; ++kt) {
    __syncthreads();
    const int kk = kt << 5;
#pragma unroll
    for (int c = 0; c < 2; ++c) {
      const int i = tid + (c << 8);
      const int row = i >> 2;
      const int gch = ((i & 3) ^ ((i >> 3) & 3)) << 3;  // swizzled source chunk
      const size_t aoff = (size_t)(bm * 128 + row) * ks + hoff + kk + gch;
      const size_t boff = (size_t)(bnc * 128 + row) * ks + hoff + kk + gch;
      g2l16(Ah + aoff, &As[0][i * 8]);
      g2l16(Bh + boff, &Bs[0][i * 8]);
      if (SPLIT)
        if (useLo) {
          g2l16(Al + aoff, &As[1][i * 8]);
          g2l16(Bl + boff, &Bs[1][i * 8]);
        }
    }
    __syncthreads();

    f16x8 a0[4], a1[4], b0[4], b1[4];
#pragma unroll
    for (int mf = 0; mf < 4; ++mf) {
      const int off = swz32(wr * 64 + mf * 16 + lrow, lgrp);
      a0[mf] = *(const f16x8*)&As[0][off];
      if (SPLIT)
        if (useLo) a1[mf] = *(const f16x8*)&As[SPLIT ? 1 : 0][off];
    }
#pragma unroll
    for (int nf = 0; nf < 4; ++nf) {
      const int off = swz32(wc * 64 + nf * 16 + lrow, lgrp);
      b0[nf] = *(const f16x8*)&Bs[0][off];
      if (SPLIT)
        if (useLo) b1[nf] = *(const f16x8*)&Bs[SPLIT ? 1 : 0][off];
    }
#pragma unroll
    for (int mf = 0; mf < 4; ++mf)
#pragma unroll
      for (int nf = 0; nf < 4; ++nf) {
        acc[mf][nf] = mfma16(a0[mf], b0[nf], acc[mf][nf]);
        if (SPLIT)
          if (useLo) {
            acc[mf][nf] = mfma16(a0[mf], b1[nf], acc[mf][nf]);
            acc[mf][nf] = mfma16(a1[mf], b0[nf], acc[mf][nf]);
          }
      }
  }

  const int rowbase = bm * 128 + wr * 64 + lgrp * 4;
  const int colbase = bnc * 128 + wc * 64 + lrow;
#pragma unroll
  for (int mf = 0; mf < 4; ++mf) {
#pragma unroll
    for (int nf = 0; nf < 4; ++nf) {
      const int gc = colbase + nf * 16;
      const float bv = (EPI == 3 && half) ? 0.f : bias[gc];
#pragma unroll
      for (int r = 0; r < 4; ++r) {
        const int gr = rowbase + mf * 16 + r;
        const float val = acc[mf][nf][r] + bv;
        if (EPI == 0) {
          const int bb = gr >> 11, tok = gr & 2047;
          const int kind = gc >> 9, hh = (gc >> 6) & 7, dd = gc & 63;
          const size_t bhp = (size_t)((bb << 3) + hh);
          const size_t qidx = (bhp * 2048 + tok) * 64 + dd;
          if (kind == 0) {
            const float sv = val * QK_SCALE;  // fold score scale + log2e into q
            const f16 hv = (f16)sv;
            oqh[qidx] = hv; oql[qidx] = (f16)(sv - (float)hv);
          } else if (kind == 1) {
            okh[qidx] = (f16)val;
          } else {
            ovT[(bhp * 64 + dd) * 2048 + tok] = (f16)val;
          }
        } else if (EPI == 1) {
          outH[(size_t)gr * N + gc] = (f16)fmaxf(val, 0.f);
        } else {
          float* o = half ? outF2 : outF;
          o[(size_t)gr * N + gc] = val;
        }
      }
    }
  }
}

// ---------------- fused flash attention: 32x32 MFMA, in-reg softmax, T15 pipeline ----------
// (R12-measured config) 1D grid 512, XCD-aware bh-major swizzle. Block 256 = 4 waves;
// wave owns 32 q-rows. Two S-register sets: iteration t ISSUES QK(t+1) MFMAs, then
// softmax(t)+PV(t) run while they execute. K/V 4-buffer LDS (64 KB), stage distance 3,
// counted vmcnt(4). fp16 output.
__global__ __launch_bounds__(256, 2) void k_attn(
    const f16* __restrict__ Qh, const f16* __restrict__ Ql,
    const f16* __restrict__ Kh, const f16* __restrict__ Vt,
    f16* __restrict__ out) {
  __shared__ f16 sK[4][64 * 64], sV[4][64 * 64];

  const int tid = threadIdx.x;
  const int wg = (blockIdx.x & 7) * 64 + (blockIdx.x >> 3);
  const int bh = wg >> 4, qt = wg & 15;
  const int w = tid >> 6, lane = tid & 63;
  const int lh = lane & 31, hh = lane >> 5;

  // Q fragments first (their vmcnt resolves before the staging waits)
  const int qrow = qt * 128 + w * 32 + lh;
  const size_t qoff = ((size_t)bh * 2048 + qrow) * 64;
  f16x8 qh8[4], ql8[4];
#pragma unroll
  for (int d = 0; d < 4; ++d) {
    const size_t o = qoff + d * 16 + hh * 8;
    qh8[d] = *(const f16x8*)(Qh + o);
    ql8[d] = *(const f16x8*)(Ql + o);
  }

  auto stage = [&](int b, int kt) {
    const size_t koff = ((size_t)bh * 2048 + (size_t)kt * 64) * 64;
    const size_t voff = (size_t)bh * 64 * 2048 + (size_t)kt * 64;
#pragma unroll
    for (int c = 0; c < 2; ++c) {
      const int i = tid + (c << 8);
      const int row = i >> 3;
      const int gch = ((i & 7) ^ (row & 7)) << 3;
      g2l16(Kh + koff + (size_t)row * 64 + gch, &sK[b][i * 8]);
      g2l16(Vt + voff + (size_t)row * 2048 + gch, &sV[b][i * 8]);
    }
  };

  stage(0, 0);
  stage(1, 1);
  stage(2, 2);

  float m_run = -3e38f;
  float l_run = 0.f;
  f32x16 oacc[2] = {};
  const f32x16 kZero = {};
  f32x16 sA[2] = {}, sB[2] = {};

  // QK MFMA issue for one tile (buffer bi) into s[2]; first MFMA uses zero-C (no resets)
  auto qk = [&](f32x16 (&s)[2], int bi) {
    __builtin_amdgcn_s_setprio(1);
    {
      const f16x8 k0 = *(const f16x8*)&sK[bi][swz64(lh, hh)];
      const f16x8 k1 = *(const f16x8*)&sK[bi][swz64(32 + lh, hh)];
      s[0] = mfma32(k0, qh8[0], kZero);
      s[0] = mfma32(k0, ql8[0], s[0]);
      s[1] = mfma32(k1, qh8[0], kZero);
      s[1] = mfma32(k1, ql8[0], s[1]);
    }
#pragma unroll
    for (int d = 1; d < 4; ++d) {
      const f16x8 k0 = *(const f16x8*)&sK[bi][swz64(lh, d * 2 + hh)];
      const f16x8 k1 = *(const f16x8*)&sK[bi][swz64(32 + lh, d * 2 + hh)];
      s[0] = mfma32(k0, qh8[d], s[0]);
      s[0] = mfma32(k0, ql8[d], s[0]);
      s[1] = mfma32(k1, qh8[d], s[1]);
      s[1] = mfma32(k1, ql8[d], s[1]);
    }
    __builtin_amdgcn_s_setprio(0);
  };

  // softmax + PV for current tile (registers s, buffer bi)
  auto sm_pv = [&](f32x16 (&s)[2], int bi) {
    float mt = s[0][0];
#pragma unroll
    for (int r = 0; r < 16; ++r) { mt = fmaxf(mt, s[0][r]); mt = fmaxf(mt, s[1][r]); }
    mt = fmaxf(mt, __shfl_xor(mt, 32, 64));
    float mcur = m_run;
    if (!__all(mt <= mcur + 8.0f)) {  // defer-max
      const float mnew = fmaxf(mcur, mt);
      const float corr = __builtin_amdgcn_exp2f(mcur - mnew);
      m_run = mnew;
      l_run *= corr;
      oacc[0] = oacc[0] * corr;
      oacc[1] = oacc[1] * corr;
      mcur = mnew;
    }
    float ps = 0.f;
    unsigned pk0[8], pk1[8];
#pragma unroll
    for (int i = 0; i < 8; ++i) {
      const float a0 = __builtin_amdgcn_exp2f(s[0][2 * i] - mcur);
      const float a1 = __builtin_amdgcn_exp2f(s[0][2 * i + 1] - mcur);
      const float b0 = __builtin_amdgcn_exp2f(s[1][2 * i] - mcur);
      const float b1 = __builtin_amdgcn_exp2f(s[1][2 * i + 1] - mcur);
      ps += (a0 + a1) + (b0 + b1);
      pk0[i] = pkrtz(a0, a1);
      pk1[i] = pkrtz(b0, b1);
    }
    ps += __shfl_xor(ps, 32, 64);
    l_run += ps;

    swap32(pk0[0], pk0[2]); swap32(pk0[1], pk0[3]);
    swap32(pk0[4], pk0[6]); swap32(pk0[5], pk0[7]);
    swap32(pk1[0], pk1[2]); swap32(pk1[1], pk1[3]);
    swap32(pk1[4], pk1[6]); swap32(pk1[5], pk1[7]);

    u32x4 pbu[4];
    pbu[0] = (u32x4){pk0[0], pk0[1], pk0[2], pk0[3]};
    pbu[1] = (u32x4){pk0[4], pk0[5], pk0[6], pk0[7]};
    pbu[2] = (u32x4){pk1[0], pk1[1], pk1[2], pk1[3]};
    pbu[3] = (u32x4){pk1[4], pk1[5], pk1[6], pk1[7]};

    __builtin_amdgcn_s_setprio(1);
#pragma unroll
    for (int s2 = 0; s2 < 4; ++s2) {
      const f16x8 pb = *(const f16x8*)&pbu[s2];
#pragma unroll
      for (int db = 0; db < 2; ++db) {
        const f16x8 v = *(const f16x8*)&sV[bi][swz64(db * 32 + lh, s2 * 2 + hh)];
        oacc[db] = mfma32(v, pb, oacc[db]);
      }
    }
    __builtin_amdgcn_s_setprio(0);
  };

  auto endwait = [&](int t) {
    if (t < 29) {
      asm volatile("s_waitcnt vmcnt(4)" ::: "memory");
    } else {
      asm volatile("s_waitcnt vmcnt(0)" ::: "memory");
    }
    __builtin_amdgcn_sched_barrier(0);
    __builtin_amdgcn_s_barrier();
    __builtin_amdgcn_sched_barrier(0);
  };

  // prologue: wait stage(0),(1)
  asm volatile("s_waitcnt vmcnt(4)" ::: "memory");
  __builtin_amdgcn_sched_barrier(0);
  __builtin_amdgcn_s_barrier();
  __builtin_amdgcn_sched_barrier(0);
  qk(sA, 0);

  for (int t = 0; t < 32; t += 2) {
    {
      if (t + 1 < 32) qk(sB, (t + 1) & 3);
      if (t + 3 < 32) stage((t + 3) & 3, t + 3);
      sm_pv(sA, t & 3);
      if (t + 1 < 32) endwait(t);
    }
    if (t + 1 < 32) {
      if (t + 2 < 32) qk(sA, (t + 2) & 3);
      if (t + 4 < 32) stage((t + 4) & 3, t + 4);
      sm_pv(sB, (t + 1) & 3);
      if (t + 2 < 32) endwait(t + 1);
    }
  }

  const int b = bh >> 3, hd = bh & 7;
  const float inv = 1.0f / l_run;
  const int trow = b * 2048 + qt * 128 + w * 32 + lh;
  f16* po = out + (size_t)trow * 512 + hd * 64;
#pragma unroll
  for (int db = 0; db < 2; ++db)
#pragma unroll
    for (int rq = 0; rq < 4; ++rq) {
      f16x4 o;
#pragma unroll
      for (int j = 0; j < 4; ++j) o[j] = (f16)(oacc[db][rq * 4 + j] * inv);
      *(f16x4*)(po + db * 32 + rq * 8 + hh * 4) = o;
    }
}

// ---------------- LN1: y = LN(x + attn) -> fp16 only (4 rows/block, wave per row) ---------
__global__ __launch_bounds__(256) void k_ln1(const float* __restrict__ X, const f16* __restrict__ R,
                                             const float* __restrict__ g, const float* __restrict__ be,
                                             f16* __restrict__ outH) {
  const int row = blockIdx.x * 4 + (threadIdx.x >> 6);
  const int t = threadIdx.x & 63;
  const size_t base = (size_t)row * 512 + t * 8;
  f32x4 x0 = *(const f32x4*)(X + base);
  f32x4 x1 = *(const f32x4*)(X + base + 4);
  const f16x8 r = *(const f16x8*)(R + base);
#pragma unroll
  for (int j = 0; j < 4; ++j) { x0[j] += (float)r[j]; x1[j] += (float)r[j + 4]; }
  float s = 0.f, ss = 0.f;
#pragma unroll
  for (int j = 0; j < 4; ++j) { s += x0[j] + x1[j]; ss += x0[j] * x0[j] + x1[j] * x1[j]; }
#pragma unroll
  for (int o = 32; o; o >>= 1) {
    s += __shfl_xor(s, o, 64);
    ss += __shfl_xor(ss, o, 64);
  }
  const float mean = s * (1.f / 512.f);
  const float var = ss * (1.f / 512.f) - mean * mean;
  const float rs = rsqrtf(var + 1e-5f);
  f32x4 g0 = *(const f32x4*)(g + t * 8);
  f32x4 g1v = *(const f32x4*)(g + t * 8 + 4);
  f32x4 b0 = *(const f32x4*)(be + t * 8);
  f32x4 b1 = *(const f32x4*)(be + t * 8 + 4);
  f16x8 hx;
#pragma unroll
  for (int j = 0; j < 4; ++j) {
    hx[j] = (f16)((x0[j] - mean) * rs * g0[j] + b0[j]);
    hx[j + 4] = (f16)((x1[j] - mean) * rs * g1v[j] + b1[j]);
  }
  *(f16x8*)(outH + base) = hx;
}

// ---------------- LN2: y = LN(x1 + ff0 + ff1) -> fp32 out (fp32 partials) ----------------
__global__ __launch_bounds__(256) void k_ln2(const f16* __restrict__ Xh,
                                             const float* __restrict__ R0, const float* __restrict__ R1,
                                             const float* __restrict__ g, const float* __restrict__ be,
                                             float* __restrict__ out) {
  const int row = blockIdx.x * 4 + (threadIdx.x >> 6);
  const int t = threadIdx.x & 63;
  const size_t base = (size_t)row * 512 + t * 8;
  const f16x8 xv = *(const f16x8*)(Xh + base);
  f32x4 r00 = *(const f32x4*)(R0 + base);
  f32x4 r01 = *(const f32x4*)(R0 + base + 4);
  f32x4 r10 = *(const f32x4*)(R1 + base);
  f32x4 r11 = *(const f32x4*)(R1 + base + 4);
  f32x4 x0, x1;
#pragma unroll
  for (int j = 0; j < 4; ++j) {
    x0[j] = (float)xv[j] + r00[j] + r10[j];
    x1[j] = (float)xv[j + 4] + r01[j] + r11[j];
  }
  float s = 0.f, ss = 0.f;
#pragma unroll
  for (int j = 0; j < 4; ++j) { s += x0[j] + x1[j]; ss += x0[j] * x0[j] + x1[j] * x1[j]; }
#pragma unroll
  for (int o = 32; o; o >>= 1) {
    s += __shfl_xor(s, o, 64);
    ss += __shfl_xor(ss, o, 64);
  }
  const float mean = s * (1.f / 512.f);
  const float var = ss * (1.f / 512.f) - mean * mean;
  const float rs = rsqrtf(var + 1e-5f);
  f32x4 g0 = *(const f32x4*)(g + t * 8);
  f32x4 g1v = *(const f32x4*)(g + t * 8 + 4);
  f32x4 b0 = *(const f32x4*)(be + t * 8);
  f32x4 b1 = *(const f32x4*)(be + t * 8 + 4);
  f32x4 y0 = (x0 - mean) * rs * g0 + b0;
  f32x4 y1 = (x1 - mean) * rs * g1v + b1;
  *(f32x4*)(out + base) = y0;
  *(f32x4*)(out + base + 4) = y1;
}

extern "C" void kernel_launch(void* const* d_in, const int* in_sizes, int n_in,
                              void* d_out, int out_size, void* d_ws, size_t ws_size,
                              hipStream_t stream) {
  (void)in_sizes; (void)n_in; (void)out_size;
  const float* x = (const float*)d_in[0];
  const float* w_qkv = (const float*)d_in[1];
  const float* b_qkv = (const float*)d_in[2];
  const float* w1 = (const float*)d_in[3];
  const float* b1 = (const float*)d_in[4];
  const float* w2 = (const float*)d_in[5];
  const float* b2 = (const float*)d_in[6];
  const float* g1 = (const float*)d_in[7];
  const float* be1 = (const float*)d_in[8];
  const float* g2 = (const float*)d_in[9];
  const float* be2 = (const float*)d_in[10];
  float* out = (float*)d_out;

  char* p = (char*)d_ws;
  auto take = [&](size_t bytes) {
    char* r = p;
    p += (bytes + 255) & ~(size_t)255;
    return r;
  };
  f16* xh = (f16*)take(8192ull * 512 * 2);
  f16* xl = (f16*)take(8192ull * 512 * 2);
  f16* wqkvTh = (f16*)take(1536ull * 512 * 2);
  f16* wqkvTl = (f16*)take(1536ull * 512 * 2);
  f16* w1T = (f16*)take(2048ull * 512 * 2);
  f16* w2T = (f16*)take(512ull * 2048 * 2);
  f16* qh = (f16*)take(32ull * 2048 * 64 * 2);
  f16* ql = (f16*)take(32ull * 2048 * 64 * 2);
  f16* kh = (f16*)take(32ull * 2048 * 64 * 2);
  f16* vT = (f16*)take(32ull * 64 * 2048 * 2);
  f16* attnH = (f16*)take(8192ull * 512 * 2);
  f16* x1h = (f16*)take(8192ull * 512 * 2);
  float* ffb0 = (float*)take(8192ull * 512 * 4);
  float* ffb1 = (float*)take(8192ull * 512 * 4);
  // reuse: hbuf [8192][2048]f16 = 33.6MB spans qh,ql,kh,vT (all dead after attn)
  f16* hbuf = qh;

  if ((size_t)(p - (char*)d_ws) > ws_size) return;  // insufficient workspace -> loud validation fail

  dim3 tb(32, 8);
  k_split<<<4096, 256, 0, stream>>>(x, xh, xl, 8192 * 512 / 4);
  k_transpose_split<true><<<dim3(1536 / 32, 512 / 32), tb, 0, stream>>>(w_qkv, 512, 1536, wqkvTh, wqkvTl);
  k_transpose_split<false><<<dim3(2048 / 32, 512 / 32), tb, 0, stream>>>(w1, 512, 2048, w1T, nullptr);
  k_transpose_split<false><<<dim3(512 / 32, 2048 / 32), tb, 0, stream>>>(w2, 2048, 512, w2T, nullptr);

  k_gemm<0, true><<<768, 256, 0, stream>>>(xh, xl, wqkvTh, wqkvTl, b_qkv,
                                           nullptr, nullptr, nullptr, qh, ql, kh, vT,
                                           8192, 1536, 512, 512, 12);
  k_attn<<<512, 256, 0, stream>>>(qh, ql, kh, vT, attnH);
  k_ln1<<<2048, 256, 0, stream>>>(x, attnH, g1, be1, x1h);
  k_gemm<1, false><<<1024, 256, 0, stream>>>(x1h, nullptr, w1T, nullptr, b1,
                                             nullptr, nullptr, hbuf, nullptr, nullptr, nullptr, nullptr,
                                             8192, 2048, 512, 512, 16);
  k_gemm<3, false><<<512, 256, 0, stream>>>(hbuf, nullptr, w2T, nullptr, b2,
                                            ffb0, ffb1, nullptr, nullptr, nullptr, nullptr, nullptr,
                                            8192, 512, 1024, 2048, 8);
  k_ln2<<<2048, 256, 0, stream>>>(x1h, ffb0, ffb1, g2, be2, out);
}

// Round 15
// 179.423 us; speedup vs baseline: 1.1073x; 1.0088x over previous
//
#include <hip/hip_runtime.h>

typedef _Float16 f16;
typedef _Float16 f16x4 __attribute__((ext_vector_type(4)));
typedef _Float16 f16x8 __attribute__((ext_vector_type(8)));
typedef float    f32x4 __attribute__((ext_vector_type(4)));
typedef float    f32x16 __attribute__((ext_vector_type(16)));
typedef unsigned int u32x4 __attribute__((ext_vector_type(4)));

#define QK_SCALE 11.5416528f  // 8 * log2(e): scores pre-scaled into exp2 domain

__device__ __forceinline__ void g2l16(const void* g, void* l) {
  __builtin_amdgcn_global_load_lds(
      (__attribute__((address_space(1))) const unsigned int*)g,
      (__attribute__((address_space(3))) unsigned int*)l, 16, 0, 0);
}

__device__ __forceinline__ f32x4 mfma16(f16x8 a, f16x8 b, f32x4 c) {
  return __builtin_amdgcn_mfma_f32_16x16x32_f16(a, b, c, 0, 0, 0);
}
__device__ __forceinline__ f32x16 mfma32(f16x8 a, f16x8 b, f32x16 c) {
  return __builtin_amdgcn_mfma_f32_32x32x16_f16(a, b, c, 0, 0, 0);
}
__device__ __forceinline__ unsigned pkrtz(float a, float b) {
  auto t = __builtin_amdgcn_cvt_pkrtz(a, b);  // __fp16 ext_vector_type(2)
  return *(unsigned*)&t;
}
// v_permlane32_swap_b32: a.upper32lanes <-> b.lower32lanes (modifies both)
__device__ __forceinline__ void swap32(unsigned& a, unsigned& b) {
  asm volatile("v_permlane32_swap_b32 %0, %1" : "+v"(a), "+v"(b));
}

// XOR-swizzled LDS offsets (f16 units). Rows of 64 f16 (8x16B chunks) / 32 f16 (4x16B chunks).
__device__ __forceinline__ int swz64(int row, int c) { return row * 64 + ((c ^ (row & 7)) << 3); }
__device__ __forceinline__ int swz32(int row, int c) { return row * 32 + ((c ^ ((row >> 1) & 3)) << 3); }

// ---------------- fp32 -> fp16 hi/lo split (vectorized) ----------------
__global__ __launch_bounds__(256) void k_split(const float* __restrict__ in,
                                               f16* __restrict__ hi, f16* __restrict__ lo, int n4) {
  int i = blockIdx.x * 256 + threadIdx.x;
  if (i >= n4) return;
  f32x4 v = ((const f32x4*)in)[i];
  f16x4 h, l;
#pragma unroll
  for (int j = 0; j < 4; ++j) {
    f16 hv = (f16)v[j];
    h[j] = hv;
    l[j] = (f16)(v[j] - (float)hv);
  }
  ((f16x4*)hi)[i] = h;
  ((f16x4*)lo)[i] = l;
}

// ---------------- transpose fp32 [K][N] -> fp16 [N][K] (hi, optional lo) ----------------
template <bool WLO>
__global__ __launch_bounds__(256) void k_transpose_split(const float* __restrict__ in, int K, int N,
                                                         f16* __restrict__ oh, f16* __restrict__ ol) {
  __shared__ float t[32][33];
  const int tx = threadIdx.x, ty = threadIdx.y;
  const int n0 = blockIdx.x * 32, k0 = blockIdx.y * 32;
#pragma unroll
  for (int j = 0; j < 4; ++j)
    t[ty + j * 8][tx] = in[(size_t)(k0 + ty + j * 8) * N + n0 + tx];
  __syncthreads();
#pragma unroll
  for (int j = 0; j < 4; ++j) {
    float v = t[tx][ty + j * 8];
    f16 hv = (f16)v;
    size_t o = (size_t)(n0 + ty + j * 8) * K + k0 + tx;
    oh[o] = hv;
    if (WLO) ol[o] = (f16)(v - (float)hv);
  }
}

// ---------------- GEMM: C[M,N] = A[M,K+] * B[K+,N], B given transposed [N][K+] -----------
// (R10-measured config: serial staging, 2D grid.) ks = row stride (split-K subviews).
// EPI 0: qkv scatter; Q tiles (bn<4) 3-term split; K,V tiles 1-term
// EPI 1: relu -> fp16 out
// EPI 3: split-K pair: bn>>2 = K-half; fp32 partials to outF (half0, +bias) / outF2 (half1)
template <int EPI, bool SPLIT>
__global__ __launch_bounds__(256, SPLIT ? 2 : 3) void k_gemm(
    const f16* __restrict__ Ah, const f16* __restrict__ Al,
    const f16* __restrict__ Bh, const f16* __restrict__ Bl,
    const float* __restrict__ bias,
    float* __restrict__ outF, float* __restrict__ outF2, f16* __restrict__ outH,
    f16* __restrict__ oqh, f16* __restrict__ oql,
    f16* __restrict__ okh, f16* __restrict__ ovT,
    int M, int N, int K, int ks) {
  constexpr int NB = SPLIT ? 2 : 1;
  __shared__ f16 As[NB][128 * 32];
  __shared__ f16 Bs[NB][128 * 32];

  const int tid = threadIdx.x;
  const int bm = blockIdx.x, bn = blockIdx.y;
  const int bnc = (EPI == 3) ? (bn & 3) : bn;
  const int half = (EPI == 3) ? (bn >> 2) : 0;
  const int hoff = half * 1024;
  const int w = tid >> 6, lane = tid & 63;
  const int wr = w >> 1, wc = w & 1;
  const int lrow = lane & 15, lgrp = lane >> 4;

  // only Q-output tiles need the hi/lo emulated-fp32 path
  const bool useLo = SPLIT && !(EPI == 0 && bn >= 4);

  f32x4 acc[4][4] = {};

  const int nkt = K >> 5;
  for (int kt = 0; kt < nkt; ++kt) {
    __syncthreads();
    const int kk = kt << 5;
#pragma unroll
    for (int c = 0; c < 2; ++c) {
      const int i = tid + (c << 8);
      const int row = i >> 2;
      const int gch = ((i & 3) ^ ((i >> 3) & 3)) << 3;  // swizzled source chunk
      const size_t aoff = (size_t)(bm * 128 + row) * ks + hoff + kk + gch;
      const size_t boff = (size_t)(bnc * 128 + row) * ks + hoff + kk + gch;
      g2l16(Ah + aoff, &As[0][i * 8]);
      g2l16(Bh + boff, &Bs[0][i * 8]);
      if (SPLIT)
        if (useLo) {
          g2l16(Al + aoff, &As[1][i * 8]);
          g2l16(Bl + boff, &Bs[1][i * 8]);
        }
    }
    __syncthreads();

    f16x8 a0[4], a1[4], b0[4], b1[4];
#pragma unroll
    for (int mf = 0; mf < 4; ++mf) {
      const int off = swz32(wr * 64 + mf * 16 + lrow, lgrp);
      a0[mf] = *(const f16x8*)&As[0][off];
      if (SPLIT)
        if (useLo) a1[mf] = *(const f16x8*)&As[SPLIT ? 1 : 0][off];
    }
#pragma unroll
    for (int nf = 0; nf < 4; ++nf) {
      const int off = swz32(wc * 64 + nf * 16 + lrow, lgrp);
      b0[nf] = *(const f16x8*)&Bs[0][off];
      if (SPLIT)
        if (useLo) b1[nf] = *(const f16x8*)&Bs[SPLIT ? 1 : 0][off];
    }
#pragma unroll
    for (int mf = 0; mf < 4; ++mf)
#pragma unroll
      for (int nf = 0; nf < 4; ++nf) {
        acc[mf][nf] = mfma16(a0[mf], b0[nf], acc[mf][nf]);
        if (SPLIT)
          if (useLo) {
            acc[mf][nf] = mfma16(a0[mf], b1[nf], acc[mf][nf]);
            acc[mf][nf] = mfma16(a1[mf], b0[nf], acc[mf][nf]);
          }
      }
  }

  const int rowbase = bm * 128 + wr * 64 + lgrp * 4;
  const int colbase = bnc * 128 + wc * 64 + lrow;
#pragma unroll
  for (int mf = 0; mf < 4; ++mf) {
#pragma unroll
    for (int nf = 0; nf < 4; ++nf) {
      const int gc = colbase + nf * 16;
      const float bv = (EPI == 3 && half) ? 0.f : bias[gc];
#pragma unroll
      for (int r = 0; r < 4; ++r) {
        const int gr = rowbase + mf * 16 + r;
        const float val = acc[mf][nf][r] + bv;
        if (EPI == 0) {
          const int bb = gr >> 11, tok = gr & 2047;
          const int kind = gc >> 9, hh = (gc >> 6) & 7, dd = gc & 63;
          const size_t bhp = (size_t)((bb << 3) + hh);
          const size_t qidx = (bhp * 2048 + tok) * 64 + dd;
          if (kind == 0) {
            const float sv = val * QK_SCALE;  // fold score scale + log2e into q
            const f16 hv = (f16)sv;
            oqh[qidx] = hv; oql[qidx] = (f16)(sv - (float)hv);
          } else if (kind == 1) {
            okh[qidx] = (f16)val;
          } else {
            ovT[(bhp * 64 + dd) * 2048 + tok] = (f16)val;
          }
        } else if (EPI == 1) {
          outH[(size_t)gr * N + gc] = (f16)fmaxf(val, 0.f);
        } else {
          float* o = half ? outF2 : outF;
          o[(size_t)gr * N + gc] = val;
        }
      }
    }
  }
}

// ---------------- fused flash attention: 32x32 MFMA, in-reg softmax, T15 pipeline ----------
// (R10/R12-measured config, 67.6 us) 1D grid 512, XCD-aware bh-major swizzle.
// Block 256 = 4 waves; wave owns 32 q-rows. Two S-register sets: iteration t ISSUES
// QK(t+1) MFMAs, then softmax(t)+PV(t) run while they execute. K/V 4-buffer LDS (64 KB),
// stage distance 3, counted vmcnt(4). fp16 output.
__global__ __launch_bounds__(256, 2) void k_attn(
    const f16* __restrict__ Qh, const f16* __restrict__ Ql,
    const f16* __restrict__ Kh, const f16* __restrict__ Vt,
    f16* __restrict__ out) {
  __shared__ f16 sK[4][64 * 64], sV[4][64 * 64];

  const int tid = threadIdx.x;
  const int wg = (blockIdx.x & 7) * 64 + (blockIdx.x >> 3);
  const int bh = wg >> 4, qt = wg & 15;
  const int w = tid >> 6, lane = tid & 63;
  const int lh = lane & 31, hh = lane >> 5;

  // Q fragments first (their vmcnt resolves before the staging waits)
  const int qrow = qt * 128 + w * 32 + lh;
  const size_t qoff = ((size_t)bh * 2048 + qrow) * 64;
  f16x8 qh8[4], ql8[4];
#pragma unroll
  for (int d = 0; d < 4; ++d) {
    const size_t o = qoff + d * 16 + hh * 8;
    qh8[d] = *(const f16x8*)(Qh + o);
    ql8[d] = *(const f16x8*)(Ql + o);
  }

  auto stage = [&](int b, int kt) {
    const size_t koff = ((size_t)bh * 2048 + (size_t)kt * 64) * 64;
    const size_t voff = (size_t)bh * 64 * 2048 + (size_t)kt * 64;
#pragma unroll
    for (int c = 0; c < 2; ++c) {
      const int i = tid + (c << 8);
      const int row = i >> 3;
      const int gch = ((i & 7) ^ (row & 7)) << 3;
      g2l16(Kh + koff + (size_t)row * 64 + gch, &sK[b][i * 8]);
      g2l16(Vt + voff + (size_t)row * 2048 + gch, &sV[b][i * 8]);
    }
  };

  stage(0, 0);
  stage(1, 1);
  stage(2, 2);

  float m_run = -3e38f;
  float l_run = 0.f;
  f32x16 oacc[2] = {};
  const f32x16 kZero = {};
  f32x16 sA[2] = {}, sB[2] = {};

  // QK MFMA issue for one tile (buffer bi) into s[2]; first MFMA uses zero-C (no resets)
  auto qk = [&](f32x16 (&s)[2], int bi) {
    __builtin_amdgcn_s_setprio(1);
    {
      const f16x8 k0 = *(const f16x8*)&sK[bi][swz64(lh, hh)];
      const f16x8 k1 = *(const f16x8*)&sK[bi][swz64(32 + lh, hh)];
      s[0] = mfma32(k0, qh8[0], kZero);
      s[0] = mfma32(k0, ql8[0], s[0]);
      s[1] = mfma32(k1, qh8[0], kZero);
      s[1] = mfma32(k1, ql8[0], s[1]);
    }
#pragma unroll
    for (int d = 1; d < 4; ++d) {
      const f16x8 k0 = *(const f16x8*)&sK[bi][swz64(lh, d * 2 + hh)];
      const f16x8 k1 = *(const f16x8*)&sK[bi][swz64(32 + lh, d * 2 + hh)];
      s[0] = mfma32(k0, qh8[d], s[0]);
      s[0] = mfma32(k0, ql8[d], s[0]);
      s[1] = mfma32(k1, qh8[d], s[1]);
      s[1] = mfma32(k1, ql8[d], s[1]);
    }
    __builtin_amdgcn_s_setprio(0);
  };

  // softmax + PV for current tile (registers s, buffer bi)
  auto sm_pv = [&](f32x16 (&s)[2], int bi) {
    float mt = s[0][0];
#pragma unroll
    for (int r = 0; r < 16; ++r) { mt = fmaxf(mt, s[0][r]); mt = fmaxf(mt, s[1][r]); }
    mt = fmaxf(mt, __shfl_xor(mt, 32, 64));
    float mcur = m_run;
    if (!__all(mt <= mcur + 8.0f)) {  // defer-max
      const float mnew = fmaxf(mcur, mt);
      const float corr = __builtin_amdgcn_exp2f(mcur - mnew);
      m_run = mnew;
      l_run *= corr;
      oacc[0] = oacc[0] * corr;
      oacc[1] = oacc[1] * corr;
      mcur = mnew;
    }
    float ps = 0.f;
    unsigned pk0[8], pk1[8];
#pragma unroll
    for (int i = 0; i < 8; ++i) {
      const float a0 = __builtin_amdgcn_exp2f(s[0][2 * i] - mcur);
      const float a1 = __builtin_amdgcn_exp2f(s[0][2 * i + 1] - mcur);
      const float b0 = __builtin_amdgcn_exp2f(s[1][2 * i] - mcur);
      const float b1 = __builtin_amdgcn_exp2f(s[1][2 * i + 1] - mcur);
      ps += (a0 + a1) + (b0 + b1);
      pk0[i] = pkrtz(a0, a1);
      pk1[i] = pkrtz(b0, b1);
    }
    ps += __shfl_xor(ps, 32, 64);
    l_run += ps;

    swap32(pk0[0], pk0[2]); swap32(pk0[1], pk0[3]);
    swap32(pk0[4], pk0[6]); swap32(pk0[5], pk0[7]);
    swap32(pk1[0], pk1[2]); swap32(pk1[1], pk1[3]);
    swap32(pk1[4], pk1[6]); swap32(pk1[5], pk1[7]);

    u32x4 pbu[4];
    pbu[0] = (u32x4){pk0[0], pk0[1], pk0[2], pk0[3]};
    pbu[1] = (u32x4){pk0[4], pk0[5], pk0[6], pk0[7]};
    pbu[2] = (u32x4){pk1[0], pk1[1], pk1[2], pk1[3]};
    pbu[3] = (u32x4){pk1[4], pk1[5], pk1[6], pk1[7]};

    __builtin_amdgcn_s_setprio(1);
#pragma unroll
    for (int s2 = 0; s2 < 4; ++s2) {
      const f16x8 pb = *(const f16x8*)&pbu[s2];
#pragma unroll
      for (int db = 0; db < 2; ++db) {
        const f16x8 v = *(const f16x8*)&sV[bi][swz64(db * 32 + lh, s2 * 2 + hh)];
        oacc[db] = mfma32(v, pb, oacc[db]);
      }
    }
    __builtin_amdgcn_s_setprio(0);
  };

  auto endwait = [&](int t) {
    if (t < 29) {
      asm volatile("s_waitcnt vmcnt(4)" ::: "memory");
    } else {
      asm volatile("s_waitcnt vmcnt(0)" ::: "memory");
    }
    __builtin_amdgcn_sched_barrier(0);
    __builtin_amdgcn_s_barrier();
    __builtin_amdgcn_sched_barrier(0);
  };

  // prologue: wait stage(0),(1)
  asm volatile("s_waitcnt vmcnt(4)" ::: "memory");
  __builtin_amdgcn_sched_barrier(0);
  __builtin_amdgcn_s_barrier();
  __builtin_amdgcn_sched_barrier(0);
  qk(sA, 0);

  for (int t = 0; t < 32; t += 2) {
    {
      if (t + 1 < 32) qk(sB, (t + 1) & 3);
      if (t + 3 < 32) stage((t + 3) & 3, t + 3);
      sm_pv(sA, t & 3);
      if (t + 1 < 32) endwait(t);
    }
    if (t + 1 < 32) {
      if (t + 2 < 32) qk(sA, (t + 2) & 3);
      if (t + 4 < 32) stage((t + 4) & 3, t + 4);
      sm_pv(sB, (t + 1) & 3);
      if (t + 2 < 32) endwait(t + 1);
    }
  }

  const int b = bh >> 3, hd = bh & 7;
  const float inv = 1.0f / l_run;
  const int trow = b * 2048 + qt * 128 + w * 32 + lh;
  f16* po = out + (size_t)trow * 512 + hd * 64;
#pragma unroll
  for (int db = 0; db < 2; ++db)
#pragma unroll
    for (int rq = 0; rq < 4; ++rq) {
      f16x4 o;
#pragma unroll
      for (int j = 0; j < 4; ++j) o[j] = (f16)(oacc[db][rq * 4 + j] * inv);
      *(f16x4*)(po + db * 32 + rq * 8 + hh * 4) = o;
    }
}

// ---------------- LN1: y = LN(x + attn) -> fp16 only (4 rows/block, wave per row) ---------
__global__ __launch_bounds__(256) void k_ln1(const float* __restrict__ X, const f16* __restrict__ R,
                                             const float* __restrict__ g, const float* __restrict__ be,
                                             f16* __restrict__ outH) {
  const int row = blockIdx.x * 4 + (threadIdx.x >> 6);
  const int t = threadIdx.x & 63;
  const size_t base = (size_t)row * 512 + t * 8;
  f32x4 x0 = *(const f32x4*)(X + base);
  f32x4 x1 = *(const f32x4*)(X + base + 4);
  const f16x8 r = *(const f16x8*)(R + base);
#pragma unroll
  for (int j = 0; j < 4; ++j) { x0[j] += (float)r[j]; x1[j] += (float)r[j + 4]; }
  float s = 0.f, ss = 0.f;
#pragma unroll
  for (int j = 0; j < 4; ++j) { s += x0[j] + x1[j]; ss += x0[j] * x0[j] + x1[j] * x1[j]; }
#pragma unroll
  for (int o = 32; o; o >>= 1) {
    s += __shfl_xor(s, o, 64);
    ss += __shfl_xor(ss, o, 64);
  }
  const float mean = s * (1.f / 512.f);
  const float var = ss * (1.f / 512.f) - mean * mean;
  const float rs = rsqrtf(var + 1e-5f);
  f32x4 g0 = *(const f32x4*)(g + t * 8);
  f32x4 g1v = *(const f32x4*)(g + t * 8 + 4);
  f32x4 b0 = *(const f32x4*)(be + t * 8);
  f32x4 b1 = *(const f32x4*)(be + t * 8 + 4);
  f16x8 hx;
#pragma unroll
  for (int j = 0; j < 4; ++j) {
    hx[j] = (f16)((x0[j] - mean) * rs * g0[j] + b0[j]);
    hx[j + 4] = (f16)((x1[j] - mean) * rs * g1v[j] + b1[j]);
  }
  *(f16x8*)(outH + base) = hx;
}

// ---------------- LN2: y = LN(x1 + ff0 + ff1) -> fp32 out (fp32 partials) ----------------
__global__ __launch_bounds__(256) void k_ln2(const f16* __restrict__ Xh,
                                             const float* __restrict__ R0, const float* __restrict__ R1,
                                             const float* __restrict__ g, const float* __restrict__ be,
                                             float* __restrict__ out) {
  const int row = blockIdx.x * 4 + (threadIdx.x >> 6);
  const int t = threadIdx.x & 63;
  const size_t base = (size_t)row * 512 + t * 8;
  const f16x8 xv = *(const f16x8*)(Xh + base);
  f32x4 r00 = *(const f32x4*)(R0 + base);
  f32x4 r01 = *(const f32x4*)(R0 + base + 4);
  f32x4 r10 = *(const f32x4*)(R1 + base);
  f32x4 r11 = *(const f32x4*)(R1 + base + 4);
  f32x4 x0, x1;
#pragma unroll
  for (int j = 0; j < 4; ++j) {
    x0[j] = (float)xv[j] + r00[j] + r10[j];
    x1[j] = (float)xv[j + 4] + r01[j] + r11[j];
  }
  float s = 0.f, ss = 0.f;
#pragma unroll
  for (int j = 0; j < 4; ++j) { s += x0[j] + x1[j]; ss += x0[j] * x0[j] + x1[j] * x1[j]; }
#pragma unroll
  for (int o = 32; o; o >>= 1) {
    s += __shfl_xor(s, o, 64);
    ss += __shfl_xor(ss, o, 64);
  }
  const float mean = s * (1.f / 512.f);
  const float var = ss * (1.f / 512.f) - mean * mean;
  const float rs = rsqrtf(var + 1e-5f);
  f32x4 g0 = *(const f32x4*)(g + t * 8);
  f32x4 g1v = *(const f32x4*)(g + t * 8 + 4);
  f32x4 b0 = *(const f32x4*)(be + t * 8);
  f32x4 b1 = *(const f32x4*)(be + t * 8 + 4);
  f32x4 y0 = (x0 - mean) * rs * g0 + b0;
  f32x4 y1 = (x1 - mean) * rs * g1v + b1;
  *(f32x4*)(out + base) = y0;
  *(f32x4*)(out + base + 4) = y1;
}

extern "C" void kernel_launch(void* const* d_in, const int* in_sizes, int n_in,
                              void* d_out, int out_size, void* d_ws, size_t ws_size,
                              hipStream_t stream) {
  (void)in_sizes; (void)n_in; (void)out_size;
  const float* x = (const float*)d_in[0];
  const float* w_qkv = (const float*)d_in[1];
  const float* b_qkv = (const float*)d_in[2];
  const float* w1 = (const float*)d_in[3];
  const float* b1 = (const float*)d_in[4];
  const float* w2 = (const float*)d_in[5];
  const float* b2 = (const float*)d_in[6];
  const float* g1 = (const float*)d_in[7];
  const float* be1 = (const float*)d_in[8];
  const float* g2 = (const float*)d_in[9];
  const float* be2 = (const float*)d_in[10];
  float* out = (float*)d_out;

  char* p = (char*)d_ws;
  auto take = [&](size_t bytes) {
    char* r = p;
    p += (bytes + 255) & ~(size_t)255;
    return r;
  };
  f16* xh = (f16*)take(8192ull * 512 * 2);
  f16* xl = (f16*)take(8192ull * 512 * 2);
  f16* wqkvTh = (f16*)take(1536ull * 512 * 2);
  f16* wqkvTl = (f16*)take(1536ull * 512 * 2);
  f16* w1T = (f16*)take(2048ull * 512 * 2);
  f16* w2T = (f16*)take(512ull * 2048 * 2);
  f16* qh = (f16*)take(32ull * 2048 * 64 * 2);
  f16* ql = (f16*)take(32ull * 2048 * 64 * 2);
  f16* kh = (f16*)take(32ull * 2048 * 64 * 2);
  f16* vT = (f16*)take(32ull * 64 * 2048 * 2);
  f16* attnH = (f16*)take(8192ull * 512 * 2);
  f16* x1h = (f16*)take(8192ull * 512 * 2);
  float* ffb0 = (float*)take(8192ull * 512 * 4);
  float* ffb1 = (float*)take(8192ull * 512 * 4);
  // reuse: hbuf [8192][2048]f16 = 33.6MB spans qh,ql,kh,vT (all dead after attn)
  f16* hbuf = qh;

  if ((size_t)(p - (char*)d_ws) > ws_size) return;  // insufficient workspace -> loud validation fail

  dim3 tb(32, 8);
  k_split<<<4096, 256, 0, stream>>>(x, xh, xl, 8192 * 512 / 4);
  k_transpose_split<true><<<dim3(1536 / 32, 512 / 32), tb, 0, stream>>>(w_qkv, 512, 1536, wqkvTh, wqkvTl);
  k_transpose_split<false><<<dim3(2048 / 32, 512 / 32), tb, 0, stream>>>(w1, 512, 2048, w1T, nullptr);
  k_transpose_split<false><<<dim3(512 / 32, 2048 / 32), tb, 0, stream>>>(w2, 2048, 512, w2T, nullptr);

  k_gemm<0, true><<<dim3(64, 12), 256, 0, stream>>>(xh, xl, wqkvTh, wqkvTl, b_qkv,
                                                    nullptr, nullptr, nullptr, qh, ql, kh, vT,
                                                    8192, 1536, 512, 512);
  k_attn<<<512, 256, 0, stream>>>(qh, ql, kh, vT, attnH);
  k_ln1<<<2048, 256, 0, stream>>>(x, attnH, g1, be1, x1h);
  k_gemm<1, false><<<dim3(64, 16), 256, 0, stream>>>(x1h, nullptr, w1T, nullptr, b1,
                                                     nullptr, nullptr, hbuf, nullptr, nullptr, nullptr, nullptr,
                                                     8192, 2048, 512, 512);
  k_gemm<3, false><<<dim3(64, 8), 256, 0, stream>>>(hbuf, nullptr, w2T, nullptr, b2,
                                                    ffb0, ffb1, nullptr, nullptr, nullptr, nullptr, nullptr,
                                                    8192, 512, 1024, 2048);
  k_ln2<<<2048, 256, 0, stream>>>(x1h, ffb0, ffb1, g2, be2, out);
}

// Round 17
// 178.729 us; speedup vs baseline: 1.1116x; 1.0039x over previous
//
#include <hip/hip_runtime.h>

typedef _Float16 f16;
typedef _Float16 f16x4 __attribute__((ext_vector_type(4)));
typedef _Float16 f16x8 __attribute__((ext_vector_type(8)));
typedef float    f32x4 __attribute__((ext_vector_type(4)));
typedef float    f32x16 __attribute__((ext_vector_type(16)));
typedef unsigned int u32x4 __attribute__((ext_vector_type(4)));

#define QK_SCALE 11.5416528f  // 8 * log2(e): scores pre-scaled into exp2 domain

__device__ __forceinline__ void g2l16(const void* g, void* l) {
  __builtin_amdgcn_global_load_lds(
      (__attribute__((address_space(1))) const unsigned int*)g,
      (__attribute__((address_space(3))) unsigned int*)l, 16, 0, 0);
}

__device__ __forceinline__ f32x4 mfma16(f16x8 a, f16x8 b, f32x4 c) {
  return __builtin_amdgcn_mfma_f32_16x16x32_f16(a, b, c, 0, 0, 0);
}
__device__ __forceinline__ f32x16 mfma32(f16x8 a, f16x8 b, f32x16 c) {
  return __builtin_amdgcn_mfma_f32_32x32x16_f16(a, b, c, 0, 0, 0);
}
__device__ __forceinline__ unsigned pkrtz(float a, float b) {
  auto t = __builtin_amdgcn_cvt_pkrtz(a, b);  // __fp16 ext_vector_type(2)
  return *(unsigned*)&t;
}
// v_permlane32_swap_b32: a.upper32lanes <-> b.lower32lanes (modifies both)
__device__ __forceinline__ void swap32(unsigned& a, unsigned& b) {
  asm volatile("v_permlane32_swap_b32 %0, %1" : "+v"(a), "+v"(b));
}

// XOR-swizzled LDS offsets (f16 units). Rows of 64 f16 (8x16B chunks) / 32 f16 (4x16B chunks).
__device__ __forceinline__ int swz64(int row, int c) { return row * 64 + ((c ^ (row & 7)) << 3); }
__device__ __forceinline__ int swz32(int row, int c) { return row * 32 + ((c ^ ((row >> 1) & 3)) << 3); }

// ---------------- fp32 -> fp16 hi/lo split (vectorized) ----------------
__global__ __launch_bounds__(256) void k_split(const float* __restrict__ in,
                                               f16* __restrict__ hi, f16* __restrict__ lo, int n4) {
  int i = blockIdx.x * 256 + threadIdx.x;
  if (i >= n4) return;
  f32x4 v = ((const f32x4*)in)[i];
  f16x4 h, l;
#pragma unroll
  for (int j = 0; j < 4; ++j) {
    f16 hv = (f16)v[j];
    h[j] = hv;
    l[j] = (f16)(v[j] - (float)hv);
  }
  ((f16x4*)hi)[i] = h;
  ((f16x4*)lo)[i] = l;
}

// ---------------- transpose fp32 [K][N] -> fp16 [N][K] (hi, optional lo) ----------------
template <bool WLO>
__global__ __launch_bounds__(256) void k_transpose_split(const float* __restrict__ in, int K, int N,
                                                         f16* __restrict__ oh, f16* __restrict__ ol) {
  __shared__ float t[32][33];
  const int tx = threadIdx.x, ty = threadIdx.y;
  const int n0 = blockIdx.x * 32, k0 = blockIdx.y * 32;
#pragma unroll
  for (int j = 0; j < 4; ++j)
    t[ty + j * 8][tx] = in[(size_t)(k0 + ty + j * 8) * N + n0 + tx];
  __syncthreads();
#pragma unroll
  for (int j = 0; j < 4; ++j) {
    float v = t[tx][ty + j * 8];
    f16 hv = (f16)v;
    size_t o = (size_t)(n0 + ty + j * 8) * K + k0 + tx;
    oh[o] = hv;
    if (WLO) ol[o] = (f16)(v - (float)hv);
  }
}

// ---------------- GEMM: C[M,N] = A[M,K+] * B[K+,N], B given transposed [N][K+] -----------
// (R10-measured config: serial staging, 2D grid.) ks = row stride (split-K subviews).
// EPI 0: qkv scatter; Q tiles (bn<4) 3-term split; K,V tiles 1-term
// EPI 1: relu -> fp16 out
// EPI 3: split-K pair: bn>>2 = K-half; fp32 partials to outF (half0, +bias) / outF2 (half1)
template <int EPI, bool SPLIT>
__global__ __launch_bounds__(256, SPLIT ? 2 : 3) void k_gemm(
    const f16* __restrict__ Ah, const f16* __restrict__ Al,
    const f16* __restrict__ Bh, const f16* __restrict__ Bl,
    const float* __restrict__ bias,
    float* __restrict__ outF, float* __restrict__ outF2, f16* __restrict__ outH,
    f16* __restrict__ oqh, f16* __restrict__ oql,
    f16* __restrict__ okh, f16* __restrict__ ovT,
    int M, int N, int K, int ks) {
  constexpr int NB = SPLIT ? 2 : 1;
  __shared__ f16 As[NB][128 * 32];
  __shared__ f16 Bs[NB][128 * 32];

  const int tid = threadIdx.x;
  const int bm = blockIdx.x, bn = blockIdx.y;
  const int bnc = (EPI == 3) ? (bn & 3) : bn;
  const int half = (EPI == 3) ? (bn >> 2) : 0;
  const int hoff = half * 1024;
  const int w = tid >> 6, lane = tid & 63;
  const int wr = w >> 1, wc = w & 1;
  const int lrow = lane & 15, lgrp = lane >> 4;

  // only Q-output tiles need the hi/lo emulated-fp32 path
  const bool useLo = SPLIT && !(EPI == 0 && bn >= 4);

  f32x4 acc[4][4] = {};

  const int nkt = K >> 5;
  for (int kt = 0; kt < nkt; ++kt) {
    __syncthreads();
    const int kk = kt << 5;
#pragma unroll
    for (int c = 0; c < 2; ++c) {
      const int i = tid + (c << 8);
      const int row = i >> 2;
      const int gch = ((i & 3) ^ ((i >> 3) & 3)) << 3;  // swizzled source chunk
      const size_t aoff = (size_t)(bm * 128 + row) * ks + hoff + kk + gch;
      const size_t boff = (size_t)(bnc * 128 + row) * ks + hoff + kk + gch;
      g2l16(Ah + aoff, &As[0][i * 8]);
      g2l16(Bh + boff, &Bs[0][i * 8]);
      if (SPLIT)
        if (useLo) {
          g2l16(Al + aoff, &As[1][i * 8]);
          g2l16(Bl + boff, &Bs[1][i * 8]);
        }
    }
    __syncthreads();

    f16x8 a0[4], a1[4], b0[4], b1[4];
#pragma unroll
    for (int mf = 0; mf < 4; ++mf) {
      const int off = swz32(wr * 64 + mf * 16 + lrow, lgrp);
      a0[mf] = *(const f16x8*)&As[0][off];
      if (SPLIT)
        if (useLo) a1[mf] = *(const f16x8*)&As[SPLIT ? 1 : 0][off];
    }
#pragma unroll
    for (int nf = 0; nf < 4; ++nf) {
      const int off = swz32(wc * 64 + nf * 16 + lrow, lgrp);
      b0[nf] = *(const f16x8*)&Bs[0][off];
      if (SPLIT)
        if (useLo) b1[nf] = *(const f16x8*)&Bs[SPLIT ? 1 : 0][off];
    }
#pragma unroll
    for (int mf = 0; mf < 4; ++mf)
#pragma unroll
      for (int nf = 0; nf < 4; ++nf) {
        acc[mf][nf] = mfma16(a0[mf], b0[nf], acc[mf][nf]);
        if (SPLIT)
          if (useLo) {
            acc[mf][nf] = mfma16(a0[mf], b1[nf], acc[mf][nf]);
            acc[mf][nf] = mfma16(a1[mf], b0[nf], acc[mf][nf]);
          }
      }
  }

  const int rowbase = bm * 128 + wr * 64 + lgrp * 4;
  const int colbase = bnc * 128 + wc * 64 + lrow;
#pragma unroll
  for (int mf = 0; mf < 4; ++mf) {
#pragma unroll
    for (int nf = 0; nf < 4; ++nf) {
      const int gc = colbase + nf * 16;
      const float bv = (EPI == 3 && half) ? 0.f : bias[gc];
#pragma unroll
      for (int r = 0; r < 4; ++r) {
        const int gr = rowbase + mf * 16 + r;
        const float val = acc[mf][nf][r] + bv;
        if (EPI == 0) {
          const int bb = gr >> 11, tok = gr & 2047;
          const int kind = gc >> 9, hh = (gc >> 6) & 7, dd = gc & 63;
          const size_t bhp = (size_t)((bb << 3) + hh);
          const size_t qidx = (bhp * 2048 + tok) * 64 + dd;
          if (kind == 0) {
            const float sv = val * QK_SCALE;  // fold score scale + log2e into q
            const f16 hv = (f16)sv;
            oqh[qidx] = hv; oql[qidx] = (f16)(sv - (float)hv);
          } else if (kind == 1) {
            okh[qidx] = (f16)val;
          } else {
            ovT[(bhp * 64 + dd) * 2048 + tok] = (f16)val;
          }
        } else if (EPI == 1) {
          outH[(size_t)gr * N + gc] = (f16)fmaxf(val, 0.f);
        } else {
          float* o = half ? outF2 : outF;
          o[(size_t)gr * N + gc] = val;
        }
      }
    }
  }
}

// ---------------- fused flash attention: 32x32 MFMA, in-reg softmax, T15 pipeline ----------
// (R10/R12/R15-measured config, 67.6 us) 1D grid 512, XCD-aware bh-major swizzle.
// Block 256 = 4 waves; wave owns 32 q-rows. Two S-register sets: iteration t ISSUES
// QK(t+1) MFMAs, then softmax(t)+PV(t) run while they execute. K/V 4-buffer LDS (64 KB),
// stage distance 3, counted vmcnt(4). fp16 output.
// NOTE (R16 lesson): counted-vmcnt schedules break if register pressure causes scratch
// spills (scratch ops count toward vmcnt) -- keep sm_pv's live set lean.
__global__ __launch_bounds__(256, 2) void k_attn(
    const f16* __restrict__ Qh, const f16* __restrict__ Ql,
    const f16* __restrict__ Kh, const f16* __restrict__ Vt,
    f16* __restrict__ out) {
  __shared__ f16 sK[4][64 * 64], sV[4][64 * 64];

  const int tid = threadIdx.x;
  const int wg = (blockIdx.x & 7) * 64 + (blockIdx.x >> 3);
  const int bh = wg >> 4, qt = wg & 15;
  const int w = tid >> 6, lane = tid & 63;
  const int lh = lane & 31, hh = lane >> 5;

  // Q fragments first (their vmcnt resolves before the staging waits)
  const int qrow = qt * 128 + w * 32 + lh;
  const size_t qoff = ((size_t)bh * 2048 + qrow) * 64;
  f16x8 qh8[4], ql8[4];
#pragma unroll
  for (int d = 0; d < 4; ++d) {
    const size_t o = qoff + d * 16 + hh * 8;
    qh8[d] = *(const f16x8*)(Qh + o);
    ql8[d] = *(const f16x8*)(Ql + o);
  }

  auto stage = [&](int b, int kt) {
    const size_t koff = ((size_t)bh * 2048 + (size_t)kt * 64) * 64;
    const size_t voff = (size_t)bh * 64 * 2048 + (size_t)kt * 64;
#pragma unroll
    for (int c = 0; c < 2; ++c) {
      const int i = tid + (c << 8);
      const int row = i >> 3;
      const int gch = ((i & 7) ^ (row & 7)) << 3;
      g2l16(Kh + koff + (size_t)row * 64 + gch, &sK[b][i * 8]);
      g2l16(Vt + voff + (size_t)row * 2048 + gch, &sV[b][i * 8]);
    }
  };

  stage(0, 0);
  stage(1, 1);
  stage(2, 2);

  float m_run = -3e38f;
  float l_run = 0.f;
  f32x16 oacc[2] = {};
  const f32x16 kZero = {};
  f32x16 sA[2] = {}, sB[2] = {};

  // QK MFMA issue for one tile (buffer bi) into s[2]; first MFMA uses zero-C (no resets)
  auto qk = [&](f32x16 (&s)[2], int bi) {
    __builtin_amdgcn_s_setprio(1);
    {
      const f16x8 k0 = *(const f16x8*)&sK[bi][swz64(lh, hh)];
      const f16x8 k1 = *(const f16x8*)&sK[bi][swz64(32 + lh, hh)];
      s[0] = mfma32(k0, qh8[0], kZero);
      s[0] = mfma32(k0, ql8[0], s[0]);
      s[1] = mfma32(k1, qh8[0], kZero);
      s[1] = mfma32(k1, ql8[0], s[1]);
    }
#pragma unroll
    for (int d = 1; d < 4; ++d) {
      const f16x8 k0 = *(const f16x8*)&sK[bi][swz64(lh, d * 2 + hh)];
      const f16x8 k1 = *(const f16x8*)&sK[bi][swz64(32 + lh, d * 2 + hh)];
      s[0] = mfma32(k0, qh8[d], s[0]);
      s[0] = mfma32(k0, ql8[d], s[0]);
      s[1] = mfma32(k1, qh8[d], s[1]);
      s[1] = mfma32(k1, ql8[d], s[1]);
    }
    __builtin_amdgcn_s_setprio(0);
  };

  // softmax + PV for current tile (registers s, buffer bi)
  auto sm_pv = [&](f32x16 (&s)[2], int bi) {
    float mt = s[0][0];
#pragma unroll
    for (int r = 0; r < 16; ++r) { mt = fmaxf(mt, s[0][r]); mt = fmaxf(mt, s[1][r]); }
    mt = fmaxf(mt, __shfl_xor(mt, 32, 64));
    float mcur = m_run;
    if (!__all(mt <= mcur + 8.0f)) {  // defer-max
      const float mnew = fmaxf(mcur, mt);
      const float corr = __builtin_amdgcn_exp2f(mcur - mnew);
      m_run = mnew;
      l_run *= corr;
      oacc[0] = oacc[0] * corr;
      oacc[1] = oacc[1] * corr;
      mcur = mnew;
    }
    float ps = 0.f;
    unsigned pk0[8], pk1[8];
#pragma unroll
    for (int i = 0; i < 8; ++i) {
      const float a0 = __builtin_amdgcn_exp2f(s[0][2 * i] - mcur);
      const float a1 = __builtin_amdgcn_exp2f(s[0][2 * i + 1] - mcur);
      const float b0 = __builtin_amdgcn_exp2f(s[1][2 * i] - mcur);
      const float b1 = __builtin_amdgcn_exp2f(s[1][2 * i + 1] - mcur);
      ps += (a0 + a1) + (b0 + b1);
      pk0[i] = pkrtz(a0, a1);
      pk1[i] = pkrtz(b0, b1);
    }
    ps += __shfl_xor(ps, 32, 64);
    l_run += ps;

    swap32(pk0[0], pk0[2]); swap32(pk0[1], pk0[3]);
    swap32(pk0[4], pk0[6]); swap32(pk0[5], pk0[7]);
    swap32(pk1[0], pk1[2]); swap32(pk1[1], pk1[3]);
    swap32(pk1[4], pk1[6]); swap32(pk1[5], pk1[7]);

    u32x4 pbu[4];
    pbu[0] = (u32x4){pk0[0], pk0[1], pk0[2], pk0[3]};
    pbu[1] = (u32x4){pk0[4], pk0[5], pk0[6], pk0[7]};
    pbu[2] = (u32x4){pk1[0], pk1[1], pk1[2], pk1[3]};
    pbu[3] = (u32x4){pk1[4], pk1[5], pk1[6], pk1[7]};

    __builtin_amdgcn_s_setprio(1);
#pragma unroll
    for (int s2 = 0; s2 < 4; ++s2) {
      const f16x8 pb = *(const f16x8*)&pbu[s2];
#pragma unroll
      for (int db = 0; db < 2; ++db) {
        const f16x8 v = *(const f16x8*)&sV[bi][swz64(db * 32 + lh, s2 * 2 + hh)];
        oacc[db] = mfma32(v, pb, oacc[db]);
      }
    }
    __builtin_amdgcn_s_setprio(0);
  };

  auto endwait = [&](int t) {
    if (t < 29) {
      asm volatile("s_waitcnt vmcnt(4)" ::: "memory");
    } else {
      asm volatile("s_waitcnt vmcnt(0)" ::: "memory");
    }
    __builtin_amdgcn_sched_barrier(0);
    __builtin_amdgcn_s_barrier();
    __builtin_amdgcn_sched_barrier(0);
  };

  // prologue: wait stage(0),(1)
  asm volatile("s_waitcnt vmcnt(4)" ::: "memory");
  __builtin_amdgcn_sched_barrier(0);
  __builtin_amdgcn_s_barrier();
  __builtin_amdgcn_sched_barrier(0);
  qk(sA, 0);

  for (int t = 0; t < 32; t += 2) {
    {
      if (t + 1 < 32) qk(sB, (t + 1) & 3);
      if (t + 3 < 32) stage((t + 3) & 3, t + 3);
      sm_pv(sA, t & 3);
      if (t + 1 < 32) endwait(t);
    }
    if (t + 1 < 32) {
      if (t + 2 < 32) qk(sA, (t + 2) & 3);
      if (t + 4 < 32) stage((t + 4) & 3, t + 4);
      sm_pv(sB, (t + 1) & 3);
      if (t + 2 < 32) endwait(t + 1);
    }
  }

  const int b = bh >> 3, hd = bh & 7;
  const float inv = 1.0f / l_run;
  const int trow = b * 2048 + qt * 128 + w * 32 + lh;
  f16* po = out + (size_t)trow * 512 + hd * 64;
#pragma unroll
  for (int db = 0; db < 2; ++db)
#pragma unroll
    for (int rq = 0; rq < 4; ++rq) {
      f16x4 o;
#pragma unroll
      for (int j = 0; j < 4; ++j) o[j] = (f16)(oacc[db][rq * 4 + j] * inv);
      *(f16x4*)(po + db * 32 + rq * 8 + hh * 4) = o;
    }
}

// ---------------- LN1: y = LN(x + attn) -> fp16 only (4 rows/block, wave per row) ---------
__global__ __launch_bounds__(256) void k_ln1(const float* __restrict__ X, const f16* __restrict__ R,
                                             const float* __restrict__ g, const float* __restrict__ be,
                                             f16* __restrict__ outH) {
  const int row = blockIdx.x * 4 + (threadIdx.x >> 6);
  const int t = threadIdx.x & 63;
  const size_t base = (size_t)row * 512 + t * 8;
  f32x4 x0 = *(const f32x4*)(X + base);
  f32x4 x1 = *(const f32x4*)(X + base + 4);
  const f16x8 r = *(const f16x8*)(R + base);
#pragma unroll
  for (int j = 0; j < 4; ++j) { x0[j] += (float)r[j]; x1[j] += (float)r[j + 4]; }
  float s = 0.f, ss = 0.f;
#pragma unroll
  for (int j = 0; j < 4; ++j) { s += x0[j] + x1[j]; ss += x0[j] * x0[j] + x1[j] * x1[j]; }
#pragma unroll
  for (int o = 32; o; o >>= 1) {
    s += __shfl_xor(s, o, 64);
    ss += __shfl_xor(ss, o, 64);
  }
  const float mean = s * (1.f / 512.f);
  const float var = ss * (1.f / 512.f) - mean * mean;
  const float rs = rsqrtf(var + 1e-5f);
  f32x4 g0 = *(const f32x4*)(g + t * 8);
  f32x4 g1v = *(const f32x4*)(g + t * 8 + 4);
  f32x4 b0 = *(const f32x4*)(be + t * 8);
  f32x4 b1 = *(const f32x4*)(be + t * 8 + 4);
  f16x8 hx;
#pragma unroll
  for (int j = 0; j < 4; ++j) {
    hx[j] = (f16)((x0[j] - mean) * rs * g0[j] + b0[j]);
    hx[j + 4] = (f16)((x1[j] - mean) * rs * g1v[j] + b1[j]);
  }
  *(f16x8*)(outH + base) = hx;
}

// ---------------- LN2: y = LN(x1 + ff0 + ff1) -> fp32 out (fp32 partials) ----------------
__global__ __launch_bounds__(256) void k_ln2(const f16* __restrict__ Xh,
                                             const float* __restrict__ R0, const float* __restrict__ R1,
                                             const float* __restrict__ g, const float* __restrict__ be,
                                             float* __restrict__ out) {
  const int row = blockIdx.x * 4 + (threadIdx.x >> 6);
  const int t = threadIdx.x & 63;
  const size_t base = (size_t)row * 512 + t * 8;
  const f16x8 xv = *(const f16x8*)(Xh + base);
  f32x4 r00 = *(const f32x4*)(R0 + base);
  f32x4 r01 = *(const f32x4*)(R0 + base + 4);
  f32x4 r10 = *(const f32x4*)(R1 + base);
  f32x4 r11 = *(const f32x4*)(R1 + base + 4);
  f32x4 x0, x1;
#pragma unroll
  for (int j = 0; j < 4; ++j) {
    x0[j] = (float)xv[j] + r00[j] + r10[j];
    x1[j] = (float)xv[j + 4] + r01[j] + r11[j];
  }
  float s = 0.f, ss = 0.f;
#pragma unroll
  for (int j = 0; j < 4; ++j) { s += x0[j] + x1[j]; ss += x0[j] * x0[j] + x1[j] * x1[j]; }
#pragma unroll
  for (int o = 32; o; o >>= 1) {
    s += __shfl_xor(s, o, 64);
    ss += __shfl_xor(ss, o, 64);
  }
  const float mean = s * (1.f / 512.f);
  const float var = ss * (1.f / 512.f) - mean * mean;
  const float rs = rsqrtf(var + 1e-5f);
  f32x4 g0 = *(const f32x4*)(g + t * 8);
  f32x4 g1v = *(const f32x4*)(g + t * 8 + 4);
  f32x4 b0 = *(const f32x4*)(be + t * 8);
  f32x4 b1 = *(const f32x4*)(be + t * 8 + 4);
  f32x4 y0 = (x0 - mean) * rs * g0 + b0;
  f32x4 y1 = (x1 - mean) * rs * g1v + b1;
  *(f32x4*)(out + base) = y0;
  *(f32x4*)(out + base + 4) = y1;
}

extern "C" void kernel_launch(void* const* d_in, const int* in_sizes, int n_in,
                              void* d_out, int out_size, void* d_ws, size_t ws_size,
                              hipStream_t stream) {
  (void)in_sizes; (void)n_in; (void)out_size;
  const float* x = (const float*)d_in[0];
  const float* w_qkv = (const float*)d_in[1];
  const float* b_qkv = (const float*)d_in[2];
  const float* w1 = (const float*)d_in[3];
  const float* b1 = (const float*)d_in[4];
  const float* w2 = (const float*)d_in[5];
  const float* b2 = (const float*)d_in[6];
  const float* g1 = (const float*)d_in[7];
  const float* be1 = (const float*)d_in[8];
  const float* g2 = (const float*)d_in[9];
  const float* be2 = (const float*)d_in[10];
  float* out = (float*)d_out;

  char* p = (char*)d_ws;
  auto take = [&](size_t bytes) {
    char* r = p;
    p += (bytes + 255) & ~(size_t)255;
    return r;
  };
  f16* xh = (f16*)take(8192ull * 512 * 2);
  f16* xl = (f16*)take(8192ull * 512 * 2);
  f16* wqkvTh = (f16*)take(1536ull * 512 * 2);
  f16* wqkvTl = (f16*)take(1536ull * 512 * 2);
  f16* w1T = (f16*)take(2048ull * 512 * 2);
  f16* w2T = (f16*)take(512ull * 2048 * 2);
  f16* qh = (f16*)take(32ull * 2048 * 64 * 2);
  f16* ql = (f16*)take(32ull * 2048 * 64 * 2);
  f16* kh = (f16*)take(32ull * 2048 * 64 * 2);
  f16* vT = (f16*)take(32ull * 64 * 2048 * 2);
  f16* attnH = (f16*)take(8192ull * 512 * 2);
  f16* x1h = (f16*)take(8192ull * 512 * 2);
  float* ffb0 = (float*)take(8192ull * 512 * 4);
  float* ffb1 = (float*)take(8192ull * 512 * 4);
  // reuse: hbuf [8192][2048]f16 = 33.6MB spans qh,ql,kh,vT (all dead after attn)
  f16* hbuf = qh;

  if ((size_t)(p - (char*)d_ws) > ws_size) return;  // insufficient workspace -> loud validation fail

  dim3 tb(32, 8);
  k_split<<<4096, 256, 0, stream>>>(x, xh, xl, 8192 * 512 / 4);
  k_transpose_split<true><<<dim3(1536 / 32, 512 / 32), tb, 0, stream>>>(w_qkv, 512, 1536, wqkvTh, wqkvTl);
  k_transpose_split<false><<<dim3(2048 / 32, 512 / 32), tb, 0, stream>>>(w1, 512, 2048, w1T, nullptr);
  k_transpose_split<false><<<dim3(512 / 32, 2048 / 32), tb, 0, stream>>>(w2, 2048, 512, w2T, nullptr);

  k_gemm<0, true><<<dim3(64, 12), 256, 0, stream>>>(xh, xl, wqkvTh, wqkvTl, b_qkv,
                                                    nullptr, nullptr, nullptr, qh, ql, kh, vT,
                                                    8192, 1536, 512, 512);
  k_attn<<<512, 256, 0, stream>>>(qh, ql, kh, vT, attnH);
  k_ln1<<<2048, 256, 0, stream>>>(x, attnH, g1, be1, x1h);
  k_gemm<1, false><<<dim3(64, 16), 256, 0, stream>>>(x1h, nullptr, w1T, nullptr, b1,
                                                     nullptr, nullptr, hbuf, nullptr, nullptr, nullptr, nullptr,
                                                     8192, 2048, 512, 512);
  k_gemm<3, false><<<dim3(64, 8), 256, 0, stream>>>(hbuf, nullptr, w2T, nullptr, b2,
                                                    ffb0, ffb1, nullptr, nullptr, nullptr, nullptr, nullptr,
                                                    8192, 512, 1024, 2048);
  k_ln2<<<2048, 256, 0, stream>>>(x1h, ffb0, ffb1, g2, be2, out);
}